// Round 9
// baseline (760.530 us; speedup 1.0000x reference)
//
#include <hip/hip_runtime.h>

// ---------------------------------------------------------------------------
// Swin block, MI355X bf16-MFMA implementation.
// Shapes: B=32, H=W=56, DIM=256, WS=7, SHIFT=3, NH=8, HD=32, N=49, nW=64,
// Bw=2048, tokens T=100352.
// R1: attn_proj: comb bias table + LDS XOR-swizzles (landed)
// R2: gemm_bt 128²: dbuf prefetch + XCD-chunked grid (landed: 678 µs)
// R3/R5/R6: pipeline/structure variants on barrier-coupled blocks (NULL)
// R4: mlp_fused (REGRESSED; reverted)
// R7: __launch_bounds__(256,4) + VALU diet: 654 µs (best)
// R8: B-direct-from-L2 (REGRESSED 745: uncoalesced 16-row fragment gather
//     on the MFMA chain; reverted — operands must stage via global_load_lds)
// R9: wave-autonomous GEMM: 64-thr blocks, each wave = independent 64x64
//     tile with PRIVATE 16KB LDS (A/B dbuf 4KB each). Sync = per-wave
//     s_waitcnt vmcnt(8) only — ZERO barriers in the K-loop (vmcnt retires
//     when the LDS write lands, m135; barriers were only ever needed for
//     cross-wave visibility). 10 independent pipelines/CU vs 4 coupled.
// ---------------------------------------------------------------------------

typedef float f4 __attribute__((ext_vector_type(4)));
typedef __bf16 b8 __attribute__((ext_vector_type(8)));

#define DEV static __device__ __forceinline__

DEV ushort f2bf(float f) {
  union { __bf16 b; ushort u; } c; c.b = (__bf16)f;   // HW v_cvt, RNE
  return c.u;
}
DEV __bf16 bfb(ushort u) { union { ushort u; __bf16 b; } c; c.u = u; return c.b; }
DEV b8 zero_b8() {
  b8 z;
#pragma unroll
  for (int i = 0; i < 8; ++i) z[i] = (__bf16)0.f;
  return z;
}
DEV void load_lds16(const void* g, void* l) {
  // lane i's 16B land at ldsbase + i*16 (wave-uniform base) [m97/m104]
  __builtin_amdgcn_global_load_lds(
      (const __attribute__((address_space(1))) unsigned int*)g,
      (__attribute__((address_space(3))) unsigned int*)l, 16, 0, 0);
}
DEV int reg3(int t) { return t < 49 ? 0 : (t < 53 ? 1 : 2); }  // shift-mask region row/col id

// ---------------------------------------------------------------------------
// weights fp32 -> bf16
__global__ __launch_bounds__(256) void cast_w(const float* a, ushort* oa, int na,
                                              const float* b, ushort* ob, int nb,
                                              const float* c, ushort* oc, int nc,
                                              const float* d, ushort* od, int nd) {
  int total = na + nb + nc + nd;
  for (int i = blockIdx.x * 256 + threadIdx.x; i < total; i += gridDim.x * 256) {
    int j = i;
    if (j < na) { oa[j] = f2bf(a[j]); continue; }
    j -= na;
    if (j < nb) { ob[j] = f2bf(b[j]); continue; }
    j -= nb;
    if (j < nc) { oc[j] = f2bf(c[j]); continue; }
    j -= nc;
    od[j] = f2bf(d[j]);
  }
}

// ---------------------------------------------------------------------------
// comb[type][h][i][j]: rel-pos bias + shift mask + pad (-1e30), fp32.
// type = (wh==7)*2 + (ww==7) — only 4 distinct window mask patterns exist.
__global__ __launch_bounds__(256) void build_bias(const float* __restrict__ rel_table,
                                                  float* __restrict__ comb) {
  const int idx = blockIdx.x * 256 + threadIdx.x;  // 4*8*64*64 = 131072
  if (idx >= 4 * 8 * 64 * 64) return;
  const int j = idx & 63, i = (idx >> 6) & 63, h = (idx >> 12) & 7, ty = idx >> 15;
  float v;
  if (i < 49 && j < 49) {
    const int iy = i / 7, ix = i - iy * 7, jy = j / 7, jx = j - jy * 7;
    const int ridx = (iy - jy + 6) * 13 + (ix - jx + 6);
    v = rel_table[ridx * 8 + h];
    const int wh = (ty & 2) ? 7 : 0, ww = (ty & 1) ? 7 : 0;
    const int irg = reg3(wh * 7 + iy) * 3 + reg3(ww * 7 + ix);
    const int jrg = reg3(wh * 7 + jy) * 3 + reg3(ww * 7 + jx);
    if (irg != jrg) v -= 100.f;
  } else {
    v = -1e30f;  // padding: exp(-inf) = 0 for j>=49; rows i>=49 harmless
  }
  comb[idx] = v;
}

// ---------------------------------------------------------------------------
// LayerNorm over 256 ch, one wave per token; optional (-3,-3) cyclic shift +
// window partition on the output index. out: bf16 (token, 256) row-major.
__global__ __launch_bounds__(256) void ln_shift(const float* __restrict__ x,
                                                const float* __restrict__ g,
                                                const float* __restrict__ bta,
                                                ushort* __restrict__ out, int shifted) {
  const int wid = threadIdx.x >> 6, lane = threadIdx.x & 63;
  const int t = blockIdx.x * 4 + wid;           // output token (windowed order if shifted)
  int src;
  if (shifted) {
    int win = t / 49, n = t - win * 49;
    int bb = win >> 6, wh = (win >> 3) & 7, ww = win & 7;
    int wy = n / 7, wx = n - wy * 7;
    int r = wh * 7 + wy + 3; if (r >= 56) r -= 56;
    int c = ww * 7 + wx + 3; if (c >= 56) c -= 56;
    src = bb * 3136 + r * 56 + c;
  } else {
    src = t;
  }
  const float4 v = *(const float4*)(x + (size_t)src * 256 + lane * 4);
  float s  = v.x + v.y + v.z + v.w;
  float s2 = v.x * v.x + v.y * v.y + v.z * v.z + v.w * v.w;
#pragma unroll
  for (int m = 32; m; m >>= 1) { s += __shfl_xor(s, m); s2 += __shfl_xor(s2, m); }
  const float mean = s * (1.f / 256.f);
  const float var  = s2 * (1.f / 256.f) - mean * mean;
  const float rs   = rsqrtf(var + 1e-5f);
  const float4 gv = *(const float4*)(g + lane * 4);
  const float4 bv = *(const float4*)(bta + lane * 4);
  ushort4 o;
  o.x = f2bf((v.x - mean) * rs * gv.x + bv.x);
  o.y = f2bf((v.y - mean) * rs * gv.y + bv.y);
  o.z = f2bf((v.z - mean) * rs * gv.z + bv.z);
  o.w = f2bf((v.w - mean) * rs * gv.w + bv.w);
  *(ushort4*)(out + (size_t)t * 256 + lane * 4) = o;
}

// ---------------------------------------------------------------------------
// Wave-autonomous bf16 GEMM: C[M,N] = A[M,K] @ B[N,K]^T. One 64-thread
// block = one wave = one 64x64 output tile with PRIVATE LDS (A/B 4KB each,
// double-buffered = 16KB). K-loop sync is the wave's own counted
// s_waitcnt vmcnt — no barriers anywhere:
//   t: issue 8 gload_lds for tile t+1 into buf^1; vmcnt(8) [tile t landed,
//      t+1's 8 stay in flight]; ds_read buf; 16 MFMA; flip.
// Staging/swizzle formulas identical to the verified gemm_bt (16-row
// segments, lk write / rsw read involution). 10 blocks/CU (LDS 160/16).
// 1D grid, XCD-chunked: lin%8 = XCD, contiguous 64-row stripes per XCD.
template <class Epi>
__global__ __launch_bounds__(64, 4) void gemm_w64(const ushort* __restrict__ A,
                                                  const ushort* __restrict__ B,
                                                  int K, int NT, Epi epi) {
  __shared__ ushort lsA[2][2048];   // 2 x 4KB : 64 rows x 32 k
  __shared__ ushort lsB[2][2048];
  const int lane = threadIdx.x;
  const int quad = lane >> 4, l16 = lane & 15;
  // XCD-chunked bijective remap (nwg = 1568*NT, divisible by 8)
  const int lin = blockIdx.x;
  const int xcd = lin & 7, j = lin >> 3;
  const int mt = xcd * 196 + j / NT;           // 196 = 1568/8 stripes per XCD
  const int nt_ = j % NT;
  const long rowA0 = (long)mt * 64;
  const long colB0 = (long)nt_ * 64;
  f4 acc[4][4];
#pragma unroll
  for (int i = 0; i < 4; ++i)
#pragma unroll
    for (int jj = 0; jj < 4; ++jj) { acc[i][jj][0] = 0.f; acc[i][jj][1] = 0.f; acc[i][jj][2] = 0.f; acc[i][jj][3] = 0.f; }
  const int lrow = lane >> 2;                            // row within 16-row segment
  const int lk = ((lane & 3) ^ ((lane >> 3) & 3)) * 8;   // swizzled global k-chunk
  const int rsw = (quad ^ ((l16 >> 1) & 3)) * 8;         // swizzled read slot
  const ushort* pa = A + (rowA0 + lrow) * (long)K + lk;
  const ushort* pb = B + (colB0 + lrow) * (long)K + lk;
  const long rstr = 16 * (long)K;                        // 16-row segment stride

  const int nsteps = K >> 5;
  // prologue: tile 0 into buf 0 (8 loads outstanding)
#pragma unroll
  for (int i = 0; i < 4; ++i) {
    load_lds16(pa + i * rstr, &lsA[0][i * 512]);
    load_lds16(pb + i * rstr, &lsB[0][i * 512]);
  }
  int cur = 0;
  for (int t = 0; t < nsteps; ++t) {
    if (t + 1 < nsteps) {
      const long k1 = (long)(t + 1) << 5;
#pragma unroll
      for (int i = 0; i < 4; ++i) {
        load_lds16(pa + i * rstr + k1, &lsA[cur ^ 1][i * 512]);
        load_lds16(pb + i * rstr + k1, &lsB[cur ^ 1][i * 512]);
      }
      asm volatile("s_waitcnt vmcnt(8)" ::: "memory");  // tile t landed; t+1 in flight
    } else {
      asm volatile("s_waitcnt vmcnt(0)" ::: "memory");  // last tile landed
    }
    b8 af[4], bfr[4];
#pragma unroll
    for (int ti = 0; ti < 4; ++ti) {
      af[ti]  = *(const b8*)&lsA[cur][(ti * 16 + l16) * 32 + rsw];
      bfr[ti] = *(const b8*)&lsB[cur][(ti * 16 + l16) * 32 + rsw];
    }
#pragma unroll
    for (int ti = 0; ti < 4; ++ti)
#pragma unroll
      for (int tj = 0; tj < 4; ++tj)
        acc[ti][tj] = __builtin_amdgcn_mfma_f32_16x16x32_bf16(af[ti], bfr[tj], acc[ti][tj], 0, 0, 0);
    cur ^= 1;
  }
  // C/D layout: row = quad*4+reg, col = lane&15 [m89/m91]
#pragma unroll
  for (int ti = 0; ti < 4; ++ti)
#pragma unroll
    for (int tj = 0; tj < 4; ++tj)
#pragma unroll
      for (int r = 0; r < 4; ++r)
        epi((int)(rowA0 + ti * 16 + quad * 4 + r),
            (int)(colB0 + tj * 16 + l16), acc[ti][tj][r]);
}

struct QkvEpi {
  ushort* out; const float* bias;
  __device__ void operator()(int r, int c, float v) const {
    v += bias[c];
    if (c < 256) v *= 0.17677669529663687f;  // HD^-0.5, pre-scale q
    out[(size_t)r * 768 + c] = f2bf(v);
  }
};
struct GeluEpi {
  ushort* out; const float* bias;
  __device__ void operator()(int r, int c, float v) const {
    v += bias[c];
    v = 0.5f * v * (1.f + erff(v * 0.70710678118654752f));  // exact gelu
    out[(size_t)r * 1024 + c] = f2bf(v);
  }
};
struct Fc2Epi {
  float* out; const float* bias;
  __device__ void operator()(int r, int c, float v) const {
    size_t i = (size_t)r * 256 + c;
    out[i] = out[i] + v + bias[c];  // += y onto x_after already in d_out
  }
};

// ---------------------------------------------------------------------------
// Attention + proj + residual + LN2, one block per window (512 thr), one
// wave/head. qkv rows: [q(256, pre-scaled) | k(256) | v(256)] bf16.
// Writes x_after (fp32, d_out) and LN2(x_after) (bf16, fc1's A) directly.
__global__ __launch_bounds__(512) void attn_proj(const ushort* __restrict__ qkv,
                                                 const float* __restrict__ comb,
                                                 const ushort* __restrict__ projw,
                                                 const float* __restrict__ projb,
                                                 const float* __restrict__ x_in,
                                                 const float* __restrict__ n2g,
                                                 const float* __restrict__ n2b,
                                                 float* __restrict__ x_out,
                                                 ushort* __restrict__ xw2) {
  __shared__ ushort sbuf[32768];  // 64KB: P (8 x 64x64) ; O staging ; fp32 x_after
  const int win = blockIdx.x;
  const int b = win >> 6, wh = (win >> 3) & 7, ww = win & 7;
  const int tid = threadIdx.x, lane = tid & 63, h = tid >> 6;
  const int quad = lane >> 4, l16 = lane & 15;
  const size_t wbase = (size_t)win * 49 * 768;

  // ---- Phase 1: S = (q*scale) @ k^T, padded to 64x64, K=32 (one MFMA/tile)
  b8 af[4], bfr[4];
#pragma unroll
  for (int ti = 0; ti < 4; ++ti) {
    const int tok = ti * 16 + l16;
    af[ti] = (tok < 49) ? *(const b8*)(qkv + wbase + (size_t)tok * 768 + h * 32 + quad * 8)
                        : zero_b8();
  }
#pragma unroll
  for (int tj = 0; tj < 4; ++tj) {
    const int key = tj * 16 + l16;
    bfr[tj] = (key < 49) ? *(const b8*)(qkv + wbase + (size_t)key * 768 + 256 + h * 32 + quad * 8)
                         : zero_b8();
  }
  f4 S[4][4];
#pragma unroll
  for (int ti = 0; ti < 4; ++ti)
#pragma unroll
    for (int tj = 0; tj < 4; ++tj) {
      S[ti][tj][0] = 0.f; S[ti][tj][1] = 0.f; S[ti][tj][2] = 0.f; S[ti][tj][3] = 0.f;
      S[ti][tj] = __builtin_amdgcn_mfma_f32_16x16x32_bf16(af[ti], bfr[tj], S[ti][tj], 0, 0, 0);
    }

  // ---- Phase 2: + precombined bias/mask table (coalesced L2 reads), row
  // softmax, P -> LDS bf16 with 16B-chunk XOR swizzle (chunk ^= row&7).
  ushort* P = sbuf + h * 4096;  // this head's 64x64
  const float* cmb = comb + ((((wh == 7) ? 2 : 0) + ((ww == 7) ? 1 : 0)) * 8 + h) * 4096;
#pragma unroll
  for (int ti = 0; ti < 4; ++ti) {
#pragma unroll
    for (int r = 0; r < 4; ++r) {
      const int i = ti * 16 + quad * 4 + r;
      const float* crow = cmb + i * 64 + l16;
      float sv[4];
#pragma unroll
      for (int tj = 0; tj < 4; ++tj) sv[tj] = S[ti][tj][r] + crow[tj * 16];
      float m = fmaxf(fmaxf(sv[0], sv[1]), fmaxf(sv[2], sv[3]));
#pragma unroll
      for (int d = 1; d < 16; d <<= 1) m = fmaxf(m, __shfl_xor(m, d));
      float sum = 0.f;
#pragma unroll
      for (int tj = 0; tj < 4; ++tj) { sv[tj] = __expf(sv[tj] - m); sum += sv[tj]; }
#pragma unroll
      for (int d = 1; d < 16; d <<= 1) sum += __shfl_xor(sum, d);
      const float inv = 1.f / sum;
      const int swz = i & 7, off = l16 & 7, cb = l16 >> 3;
#pragma unroll
      for (int tj = 0; tj < 4; ++tj) {
        const int cc = tj * 2 + cb;
        P[i * 64 + (((cc ^ swz) << 3) | off)] = f2bf(sv[tj] * inv);
      }
    }
  }

  // ---- Phase 3: O = P @ V (K=64 keys, 2 MFMAs per 16x16 out tile)
  f4 O[4][2];
#pragma unroll
  for (int ti = 0; ti < 4; ++ti)
#pragma unroll
    for (int tn = 0; tn < 2; ++tn) { O[ti][tn][0] = 0.f; O[ti][tn][1] = 0.f; O[ti][tn][2] = 0.f; O[ti][tn][3] = 0.f; }
#pragma unroll
  for (int kt = 0; kt < 2; ++kt) {
    b8 vb[2];
#pragma unroll
    for (int tn = 0; tn < 2; ++tn)
#pragma unroll
      for (int j = 0; j < 8; ++j) {
        const int key = kt * 32 + quad * 8 + j;  // B-frag: b[j]=V[k=quad*8+j][n=lane&15]
        vb[tn][j] = (key < 49)
            ? bfb(qkv[wbase + (size_t)key * 768 + 512 + h * 32 + tn * 16 + l16])
            : (__bf16)0.f;
      }
#pragma unroll
    for (int ti = 0; ti < 4; ++ti) {
      const int row = ti * 16 + l16;
      const b8 pa = *(const b8*)(P + row * 64 + (((kt * 4 + quad) ^ (row & 7)) << 3));
#pragma unroll
      for (int tn = 0; tn < 2; ++tn)
        O[ti][tn] = __builtin_amdgcn_mfma_f32_16x16x32_bf16(pa, vb[tn], O[ti][tn], 0, 0, 0);
    }
  }

  // ---- Phase 4: stage O (64 x 256 bf16) in LDS, XOR-swizzled (aliases P)
  __syncthreads();
  ushort* ob = sbuf;
#pragma unroll
  for (int ti = 0; ti < 4; ++ti)
#pragma unroll
    for (int tn = 0; tn < 2; ++tn)
#pragma unroll
      for (int r = 0; r < 4; ++r) {
        const int tok = ti * 16 + quad * 4 + r;
        const int cc = h * 4 + tn * 2 + (l16 >> 3);
        ob[tok * 256 + (((cc ^ (tok & 7)) << 3) | (l16 & 7))] = f2bf(O[ti][tn][r]);
      }
  __syncthreads();

  // ---- Phase 5: proj: (64x256) @ projw(256,256)^T; wave h owns 32 out cols
  f4 C[4][2];
#pragma unroll
  for (int ti = 0; ti < 4; ++ti)
#pragma unroll
    for (int tn = 0; tn < 2; ++tn) { C[ti][tn][0] = 0.f; C[ti][tn][1] = 0.f; C[ti][tn][2] = 0.f; C[ti][tn][3] = 0.f; }
  for (int k0 = 0; k0 < 256; k0 += 32) {
    b8 bw[2];
#pragma unroll
    for (int tn = 0; tn < 2; ++tn)
      bw[tn] = *(const b8*)(projw + (size_t)(h * 32 + tn * 16 + l16) * 256 + k0 + quad * 8);
#pragma unroll
    for (int ti = 0; ti < 4; ++ti) {
      const int row = ti * 16 + l16;
      const b8 pa = *(const b8*)(ob + row * 256 + ((((k0 >> 3) + quad) ^ (row & 7)) << 3));
#pragma unroll
      for (int tn = 0; tn < 2; ++tn)
        C[ti][tn] = __builtin_amdgcn_mfma_f32_16x16x32_bf16(pa, bw[tn], C[ti][tn], 0, 0, 0);
    }
  }

  // ---- Phase 6: stage proj output (64x256 fp32, 64KB) in LDS, float4-chunk
  // XOR swizzle (chunk ^= tok&7) to spread write banks.
  __syncthreads();  // all waves done reading ob
  float* fbuf = (float*)sbuf;
#pragma unroll
  for (int ti = 0; ti < 4; ++ti)
#pragma unroll
    for (int r = 0; r < 4; ++r) {
      const int tok = ti * 16 + quad * 4 + r;
      const int swz = tok & 7;
#pragma unroll
      for (int tn = 0; tn < 2; ++tn) {
        const int c4 = h * 8 + tn * 4 + (l16 >> 2);
        fbuf[tok * 256 + (((c4 ^ swz) << 2) | (l16 & 3))] = C[ti][tn][r];
      }
    }
  __syncthreads();

  // ---- Phase 7: per-token: x_after = proj + projb + shortcut (inverse
  // shift), store fp32; fused LN2 -> bf16 xw2 (raster token order).
  for (int t = h; t < 49; t += 8) {
    const int wy = t / 7, wx = t - wy * 7;
    int rr = wh * 7 + wy + 3; if (rr >= 56) rr -= 56;
    int cc = ww * 7 + wx + 3; if (cc >= 56) cc -= 56;
    const size_t base = ((size_t)b * 3136 + rr * 56 + cc) * 256;
    // swizzled read: location chunk lane^(t&7) holds column chunk `lane`
    float4 v = *(float4*)&fbuf[t * 256 + ((lane ^ (t & 7)) << 2)];
    const float4 pb = *(const float4*)(projb + lane * 4);
    const float4 xr = *(const float4*)(x_in + base + lane * 4);
    v.x += pb.x + xr.x; v.y += pb.y + xr.y; v.z += pb.z + xr.z; v.w += pb.w + xr.w;
    *(float4*)(x_out + base + lane * 4) = v;
    float s  = v.x + v.y + v.z + v.w;
    float s2 = v.x * v.x + v.y * v.y + v.z * v.z + v.w * v.w;
#pragma unroll
    for (int m = 32; m; m >>= 1) { s += __shfl_xor(s, m); s2 += __shfl_xor(s2, m); }
    const float mean = s * (1.f / 256.f);
    const float var  = s2 * (1.f / 256.f) - mean * mean;
    const float rs   = rsqrtf(var + 1e-5f);
    const float4 gv = *(const float4*)(n2g + lane * 4);
    const float4 bv = *(const float4*)(n2b + lane * 4);
    ushort4 o;
    o.x = f2bf((v.x - mean) * rs * gv.x + bv.x);
    o.y = f2bf((v.y - mean) * rs * gv.y + bv.y);
    o.z = f2bf((v.z - mean) * rs * gv.z + bv.z);
    o.w = f2bf((v.w - mean) * rs * gv.w + bv.w);
    *(ushort4*)(xw2 + base + lane * 4) = o;
  }
}

// ---------------------------------------------------------------------------
extern "C" void kernel_launch(void* const* d_in, const int* in_sizes, int n_in,
                              void* d_out, int out_size, void* d_ws, size_t ws_size,
                              hipStream_t stream) {
  const float* x     = (const float*)d_in[0];
  const float* n1g   = (const float*)d_in[1];
  const float* n1b   = (const float*)d_in[2];
  const float* qkvw  = (const float*)d_in[3];
  const float* qkvb  = (const float*)d_in[4];
  const float* relt  = (const float*)d_in[5];
  const float* projw = (const float*)d_in[6];
  const float* projb = (const float*)d_in[7];
  const float* n2g   = (const float*)d_in[8];
  const float* n2b   = (const float*)d_in[9];
  const float* fc1w  = (const float*)d_in[10];
  const float* fc1b  = (const float*)d_in[11];
  const float* fc2w  = (const float*)d_in[12];
  const float* fc2b  = (const float*)d_in[13];
  float* out = (float*)d_out;
  char* ws = (char*)d_ws;

  // ws layout:
  //   [0, 51.4MB)        xw: LN1 windowed bf16 A; reused as LN2 output (xw2)
  //   [51.4, 256.9MB)    qkv bf16 (154.1MB); reused as fc1 hidden (205.5MB)
  //   [205.5, 206.0MB)   comb bias/mask table (512KB) — dead space until fc1
  //                      overwrites it (attn_proj has finished by then)
  //   [256.9, 258.5MB)   bf16 weights
  ushort* xw     = (ushort*)ws;
  ushort* qkv    = (ushort*)(ws + 51380224);
  ushort* hidden = qkv;
  float*  comb   = (float*)(ws + 205520896);   // after qkv's 154,140,672 bytes
  ushort* wqkv   = (ushort*)(ws + 51380224 + 205520896);
  ushort* wproj  = wqkv + 196608;
  ushort* wfc1   = wproj + 65536;
  ushort* wfc2   = wfc1 + 262144;

  cast_w<<<768, 256, 0, stream>>>(qkvw, wqkv, 196608, projw, wproj, 65536,
                                  fc1w, wfc1, 262144, fc2w, wfc2, 262144);
  build_bias<<<512, 256, 0, stream>>>(relt, comb);
  // LN1 + shift + window partition -> bf16
  ln_shift<<<25088, 256, 0, stream>>>(x, n1g, n1b, xw, 1);
  // qkv: (100352,256) @ (768,256)^T — wave-autonomous, NT=12
  gemm_w64<<<18816, 64, 0, stream>>>(xw, wqkv, 256, 12, QkvEpi{qkv, qkvb});
  // attention + proj + residual + inverse shift + LN2 -> d_out, xw (bf16)
  attn_proj<<<2048, 512, 0, stream>>>(qkv, comb, wproj, projb, x, n2g, n2b, out, xw);
  // fc1 + gelu: (100352,256) @ (1024,256)^T — NT=16
  gemm_w64<<<25088, 64, 0, stream>>>(xw, wfc1, 256, 16, GeluEpi{hidden, fc1b});
  // fc2 + residual: (100352,1024) @ (256,1024)^T, += into d_out — NT=4
  gemm_w64<<<6272, 64, 0, stream>>>(hidden, wfc2, 1024, 4, Fc2Epi{out, fc2b});
}

// Round 11
// 698.104 us; speedup vs baseline: 1.0894x; 1.0894x over previous
//
#include <hip/hip_runtime.h>

// ---------------------------------------------------------------------------
// Swin block, MI355X bf16-MFMA implementation.
// Shapes: B=32, H=W=56, DIM=256, WS=7, SHIFT=3, NH=8, HD=32, N=49, nW=64,
// Bw=2048, tokens T=100352.
// R1: attn_proj: comb bias table + LDS XOR-swizzles (landed)
// R2: gemm_bt 128²: dbuf prefetch + XCD-chunked grid (landed: 678 µs)
// R3/R5/R6: schedule variants on barrier-coupled blocks (NULL)
// R4: mlp_fused v1 (REGRESSED: 8 lockstep barriers/block)
// R7: __launch_bounds__(256,4) + VALU diet: 654 µs (best)
// R8: B-direct in BARRIERED loop (REGRESSED) / R9: wave-autonomous (REGRESSED)
// R10: mlp2 fusion (FAILED: lsA is 32KB but lsH started at +16KB, and no
//      barrier between fc1's A-reads and gelu's H-writes -> cross-wave race)
// R11: fix — lsH fully aliases lsA (both at ls[0]), ONE added barrier after
//      the fc1 loop ("all waves done reading A") before H overwrites it.
//      LDS = 128KB exactly. Still zero barriers inside either K-loop.
// ---------------------------------------------------------------------------

typedef float f4 __attribute__((ext_vector_type(4)));
typedef __bf16 b8 __attribute__((ext_vector_type(8)));

#define DEV static __device__ __forceinline__

DEV ushort f2bf(float f) {
  union { __bf16 b; ushort u; } c; c.b = (__bf16)f;   // HW v_cvt, RNE
  return c.u;
}
DEV __bf16 bfb(ushort u) { union { ushort u; __bf16 b; } c; c.u = u; return c.b; }
DEV b8 zero_b8() {
  b8 z;
#pragma unroll
  for (int i = 0; i < 8; ++i) z[i] = (__bf16)0.f;
  return z;
}
DEV void load_lds16(const void* g, void* l) {
  // lane i's 16B land at ldsbase + i*16 (wave-uniform base) [m97/m104]
  __builtin_amdgcn_global_load_lds(
      (const __attribute__((address_space(1))) unsigned int*)g,
      (__attribute__((address_space(3))) unsigned int*)l, 16, 0, 0);
}
DEV int reg3(int t) { return t < 49 ? 0 : (t < 53 ? 1 : 2); }  // shift-mask region row/col id

// ---------------------------------------------------------------------------
// weights fp32 -> bf16
__global__ __launch_bounds__(256) void cast_w(const float* a, ushort* oa, int na,
                                              const float* b, ushort* ob, int nb,
                                              const float* c, ushort* oc, int nc,
                                              const float* d, ushort* od, int nd) {
  int total = na + nb + nc + nd;
  for (int i = blockIdx.x * 256 + threadIdx.x; i < total; i += gridDim.x * 256) {
    int j = i;
    if (j < na) { oa[j] = f2bf(a[j]); continue; }
    j -= na;
    if (j < nb) { ob[j] = f2bf(b[j]); continue; }
    j -= nb;
    if (j < nc) { oc[j] = f2bf(c[j]); continue; }
    j -= nc;
    od[j] = f2bf(d[j]);
  }
}

// ---------------------------------------------------------------------------
// comb[type][h][i][j]: rel-pos bias + shift mask + pad (-1e30), fp32.
// type = (wh==7)*2 + (ww==7) — only 4 distinct window mask patterns exist.
__global__ __launch_bounds__(256) void build_bias(const float* __restrict__ rel_table,
                                                  float* __restrict__ comb) {
  const int idx = blockIdx.x * 256 + threadIdx.x;  // 4*8*64*64 = 131072
  if (idx >= 4 * 8 * 64 * 64) return;
  const int j = idx & 63, i = (idx >> 6) & 63, h = (idx >> 12) & 7, ty = idx >> 15;
  float v;
  if (i < 49 && j < 49) {
    const int iy = i / 7, ix = i - iy * 7, jy = j / 7, jx = j - jy * 7;
    const int ridx = (iy - jy + 6) * 13 + (ix - jx + 6);
    v = rel_table[ridx * 8 + h];
    const int wh = (ty & 2) ? 7 : 0, ww = (ty & 1) ? 7 : 0;
    const int irg = reg3(wh * 7 + iy) * 3 + reg3(ww * 7 + ix);
    const int jrg = reg3(wh * 7 + jy) * 3 + reg3(ww * 7 + jx);
    if (irg != jrg) v -= 100.f;
  } else {
    v = -1e30f;  // padding: exp(-inf) = 0 for j>=49; rows i>=49 harmless
  }
  comb[idx] = v;
}

// ---------------------------------------------------------------------------
// LayerNorm over 256 ch, one wave per token; optional (-3,-3) cyclic shift +
// window partition on the output index. out: bf16 (token, 256) row-major.
__global__ __launch_bounds__(256) void ln_shift(const float* __restrict__ x,
                                                const float* __restrict__ g,
                                                const float* __restrict__ bta,
                                                ushort* __restrict__ out, int shifted) {
  const int wid = threadIdx.x >> 6, lane = threadIdx.x & 63;
  const int t = blockIdx.x * 4 + wid;           // output token (windowed order if shifted)
  int src;
  if (shifted) {
    int win = t / 49, n = t - win * 49;
    int bb = win >> 6, wh = (win >> 3) & 7, ww = win & 7;
    int wy = n / 7, wx = n - wy * 7;
    int r = wh * 7 + wy + 3; if (r >= 56) r -= 56;
    int c = ww * 7 + wx + 3; if (c >= 56) c -= 56;
    src = bb * 3136 + r * 56 + c;
  } else {
    src = t;
  }
  const float4 v = *(const float4*)(x + (size_t)src * 256 + lane * 4);
  float s  = v.x + v.y + v.z + v.w;
  float s2 = v.x * v.x + v.y * v.y + v.z * v.z + v.w * v.w;
#pragma unroll
  for (int m = 32; m; m >>= 1) { s += __shfl_xor(s, m); s2 += __shfl_xor(s2, m); }
  const float mean = s * (1.f / 256.f);
  const float var  = s2 * (1.f / 256.f) - mean * mean;
  const float rs   = rsqrtf(var + 1e-5f);
  const float4 gv = *(const float4*)(g + lane * 4);
  const float4 bv = *(const float4*)(bta + lane * 4);
  ushort4 o;
  o.x = f2bf((v.x - mean) * rs * gv.x + bv.x);
  o.y = f2bf((v.y - mean) * rs * gv.y + bv.y);
  o.z = f2bf((v.z - mean) * rs * gv.z + bv.z);
  o.w = f2bf((v.w - mean) * rs * gv.w + bv.w);
  *(ushort4*)(out + (size_t)t * 256 + lane * 4) = o;
}

// ---------------------------------------------------------------------------
// Generic bf16 GEMM (R7 form, 654 µs config): C[M,N] = A[M,K] @ B[N,K]^T,
// 128x128 tile, BK=32, 256 thr (2x2 waves), gload_lds staging, dbuf.
// __launch_bounds__(256,4) -> 4 blocks/CU.
template <class Epi>
__global__ __launch_bounds__(256, 4) void gemm_bt(const ushort* __restrict__ A,
                                                  const ushort* __restrict__ B,
                                                  int K, int NT, Epi epi) {
  __shared__ ushort lsA[2][128 * 32];
  __shared__ ushort lsB[2][128 * 32];
  const int tid = threadIdx.x;
  const int lane = tid & 63, wid = tid >> 6;
  const int quad = lane >> 4, l16 = lane & 15;
  const int wm = wid >> 1, wn = wid & 1;
  // XCD-chunked bijective remap (nwg = 784*NT, divisible by 8)
  const int lin = blockIdx.x;
  const int xcd = lin & 7, j = lin >> 3;
  const int mt = xcd * 98 + j / NT;            // 98 = 784/8 stripes per XCD
  const int nt_ = j % NT;
  const long rowA0 = (long)mt * 128;
  const long colB0 = (long)nt_ * 128;
  f4 acc[4][4];
#pragma unroll
  for (int i = 0; i < 4; ++i)
#pragma unroll
    for (int jj = 0; jj < 4; ++jj) { acc[i][jj][0] = 0.f; acc[i][jj][1] = 0.f; acc[i][jj][2] = 0.f; acc[i][jj][3] = 0.f; }
  const int lrow = lane >> 2;
  const int lk = ((lane & 3) ^ ((lane >> 3) & 3)) * 8;   // swizzled global k-chunk
  const int rsw = (quad ^ ((l16 >> 1) & 3)) * 8;         // swizzled read slot
  const int seg0 = wid * 2, seg1 = wid * 2 + 1;
  const ushort* pa0 = A + (rowA0 + seg0 * 16 + lrow) * (long)K + lk;
  const ushort* pa1 = A + (rowA0 + seg1 * 16 + lrow) * (long)K + lk;
  const ushort* pb0 = B + (colB0 + seg0 * 16 + lrow) * (long)K + lk;
  const ushort* pb1 = B + (colB0 + seg1 * 16 + lrow) * (long)K + lk;

  const int nsteps = K >> 5;
  load_lds16(pa0, &lsA[0][seg0 * 512]);
  load_lds16(pa1, &lsA[0][seg1 * 512]);
  load_lds16(pb0, &lsB[0][seg0 * 512]);
  load_lds16(pb1, &lsB[0][seg1 * 512]);
  __syncthreads();

  for (int t = 0; t < nsteps; ++t) {
    const int cur = t & 1;
    if (t + 1 < nsteps) {
      const int k1 = (t + 1) << 5;
      load_lds16(pa0 + k1, &lsA[cur ^ 1][seg0 * 512]);
      load_lds16(pa1 + k1, &lsA[cur ^ 1][seg1 * 512]);
      load_lds16(pb0 + k1, &lsB[cur ^ 1][seg0 * 512]);
      load_lds16(pb1 + k1, &lsB[cur ^ 1][seg1 * 512]);
    }
    b8 af[4], bfr[4];
#pragma unroll
    for (int ti = 0; ti < 4; ++ti)
      af[ti] = *(const b8*)&lsA[cur][(wm * 64 + ti * 16 + l16) * 32 + rsw];
#pragma unroll
    for (int tj = 0; tj < 4; ++tj)
      bfr[tj] = *(const b8*)&lsB[cur][(wn * 64 + tj * 16 + l16) * 32 + rsw];
#pragma unroll
    for (int ti = 0; ti < 4; ++ti)
#pragma unroll
      for (int tj = 0; tj < 4; ++tj)
        acc[ti][tj] = __builtin_amdgcn_mfma_f32_16x16x32_bf16(af[ti], bfr[tj], acc[ti][tj], 0, 0, 0);
    __syncthreads();
  }
  // C/D layout: row = quad*4+reg, col = lane&15 [m89/m91]
#pragma unroll
  for (int ti = 0; ti < 4; ++ti)
#pragma unroll
    for (int tj = 0; tj < 4; ++tj)
#pragma unroll
      for (int r = 0; r < 4; ++r)
        epi((int)(rowA0 + wm * 64 + ti * 16 + quad * 4 + r),
            (int)(colB0 + wn * 64 + tj * 16 + l16), acc[ti][tj][r]);
}

struct QkvEpi {
  ushort* out; const float* bias;
  __device__ void operator()(int r, int c, float v) const {
    v += bias[c];
    if (c < 256) v *= 0.17677669529663687f;  // HD^-0.5, pre-scale q
    out[(size_t)r * 768 + c] = f2bf(v);
  }
};

// ---------------------------------------------------------------------------
// Fused MLP v2 (attn-phase-5 shape): out += fc2(gelu(fc1(xw2)+b1))+b2 per
// 64-token stripe. 512 thr / 8 waves. LDS (dynamic, 128KB): A 64x256 bf16
// (gemm staging layout, 32KB) at ls[0], H 64x1024 bf16 (XOR-swizzled,
// 128KB) ALIASES it from ls[0] — A is dead after fc1; a barrier separates
// the last A-read from the first H-write (R10's missing barrier).
// fc1: wave h owns H cols [h*128,+128); K=256 fully unrolled, W1 fragments
// direct from L2, NO barriers inside. fc2: wave h owns out cols [h*32,+32);
// K=1024 (unroll 8), W2 direct from L2, H from LDS. 3 barriers per block.
__global__ __launch_bounds__(512, 2) void mlp2(const ushort* __restrict__ A,
                                               const ushort* __restrict__ w1,
                                               const float* __restrict__ b1,
                                               const ushort* __restrict__ w2,
                                               const float* __restrict__ b2,
                                               float* __restrict__ out) {
  extern __shared__ __align__(16) ushort ls[];   // 128KB
  ushort* lsA = ls;          // [0, 16384) ushorts = 32KB, dead after fc1
  ushort* lsH = ls;          // [0, 65536) ushorts = 128KB, written after bar
  const int tid = threadIdx.x, lane = tid & 63, h = tid >> 6;
  const int quad = lane >> 4, l16 = lane & 15;
  const long r0 = (long)blockIdx.x * 64;
  const int lrow = lane >> 2;
  const int lk = ((lane & 3) ^ ((lane >> 3) & 3)) * 8;   // swizzled global k-chunk
  const int rsw = (quad ^ ((l16 >> 1) & 3)) * 8;         // swizzled read slot

  // ---- stage A (64x256, 32KB): wave h stages k-chunk h (4 segments x 1KB)
#pragma unroll
  for (int seg = 0; seg < 4; ++seg)
    load_lds16(A + (r0 + seg * 16 + lrow) * 256 + h * 32 + lk,
               &lsA[h * 2048 + seg * 512]);
  __syncthreads();   // A resident block-wide (barrier drains vmcnt)

  // ---- fc1: acc1[4][8] = A @ W1^T for cols [h*128, +128), K=256 unrolled
  f4 a1[4][8];
#pragma unroll
  for (int ti = 0; ti < 4; ++ti)
#pragma unroll
    for (int tn = 0; tn < 8; ++tn) { a1[ti][tn][0] = 0.f; a1[ti][tn][1] = 0.f; a1[ti][tn][2] = 0.f; a1[ti][tn][3] = 0.f; }
#pragma unroll
  for (int kc = 0; kc < 8; ++kc) {
    b8 bw[8];
#pragma unroll
    for (int tn = 0; tn < 8; ++tn)
      bw[tn] = *(const b8*)(w1 + (size_t)(h * 128 + tn * 16 + l16) * 256 + kc * 32 + quad * 8);
    b8 af[4];
#pragma unroll
    for (int ti = 0; ti < 4; ++ti)
      af[ti] = *(const b8*)&lsA[kc * 2048 + (ti * 16 + l16) * 32 + rsw];
#pragma unroll
    for (int ti = 0; ti < 4; ++ti)
#pragma unroll
      for (int tn = 0; tn < 8; ++tn)
        a1[ti][tn] = __builtin_amdgcn_mfma_f32_16x16x32_bf16(af[ti], bw[tn], a1[ti][tn], 0, 0, 0);
  }
  __syncthreads();   // ALL waves done reading A before H overwrites it (R11 fix)

  // ---- bias + exact gelu -> H (16B-chunk XOR swizzle: cc ^= row&7)
  float b1v[8];
#pragma unroll
  for (int tn = 0; tn < 8; ++tn) b1v[tn] = b1[h * 128 + tn * 16 + l16];
#pragma unroll
  for (int ti = 0; ti < 4; ++ti)
#pragma unroll
    for (int tn = 0; tn < 8; ++tn)
#pragma unroll
      for (int rr = 0; rr < 4; ++rr) {
        const int row = ti * 16 + quad * 4 + rr;
        const int cc = h * 16 + tn * 2 + (l16 >> 3);   // 16B chunk of col
        float v = a1[ti][tn][rr] + b1v[tn];
        v = 0.5f * v * (1.f + erff(v * 0.70710678118654752f));
        lsH[row * 1024 + (((cc ^ (row & 7)) << 3) | (l16 & 7))] = f2bf(v);
      }
  __syncthreads();   // H visible block-wide

  // ---- fc2: acc2[4][2] = H @ W2^T for cols [h*32, +32), K=1024
  f4 a2[4][2];
#pragma unroll
  for (int ti = 0; ti < 4; ++ti)
#pragma unroll
    for (int tn = 0; tn < 2; ++tn) { a2[ti][tn][0] = 0.f; a2[ti][tn][1] = 0.f; a2[ti][tn][2] = 0.f; a2[ti][tn][3] = 0.f; }
#pragma unroll 8
  for (int k0 = 0; k0 < 1024; k0 += 32) {
    b8 bw2[2];
#pragma unroll
    for (int tn = 0; tn < 2; ++tn)
      bw2[tn] = *(const b8*)(w2 + (size_t)(h * 32 + tn * 16 + l16) * 1024 + k0 + quad * 8);
#pragma unroll
    for (int ti = 0; ti < 4; ++ti) {
      const int row = ti * 16 + l16;
      const b8 pa = *(const b8*)&lsH[row * 1024 + ((((k0 >> 3) + quad) ^ (row & 7)) << 3)];
#pragma unroll
      for (int tn = 0; tn < 2; ++tn)
        a2[ti][tn] = __builtin_amdgcn_mfma_f32_16x16x32_bf16(pa, bw2[tn], a2[ti][tn], 0, 0, 0);
    }
  }

  // ---- epilogue: out += C + b2
#pragma unroll
  for (int tn = 0; tn < 2; ++tn) {
    const float bb = b2[h * 32 + tn * 16 + l16];
#pragma unroll
    for (int ti = 0; ti < 4; ++ti)
#pragma unroll
      for (int rr = 0; rr < 4; ++rr) {
        const size_t i = (size_t)(r0 + ti * 16 + quad * 4 + rr) * 256 + h * 32 + tn * 16 + l16;
        out[i] += a2[ti][tn][rr] + bb;
      }
  }
}

// ---------------------------------------------------------------------------
// Attention + proj + residual + LN2, one block per window (512 thr), one
// wave/head. qkv rows: [q(256, pre-scaled) | k(256) | v(256)] bf16.
// Writes x_after (fp32, d_out) and LN2(x_after) (bf16, fc1's A) directly.
__global__ __launch_bounds__(512) void attn_proj(const ushort* __restrict__ qkv,
                                                 const float* __restrict__ comb,
                                                 const ushort* __restrict__ projw,
                                                 const float* __restrict__ projb,
                                                 const float* __restrict__ x_in,
                                                 const float* __restrict__ n2g,
                                                 const float* __restrict__ n2b,
                                                 float* __restrict__ x_out,
                                                 ushort* __restrict__ xw2) {
  __shared__ ushort sbuf[32768];  // 64KB: P (8 x 64x64) ; O staging ; fp32 x_after
  const int win = blockIdx.x;
  const int b = win >> 6, wh = (win >> 3) & 7, ww = win & 7;
  const int tid = threadIdx.x, lane = tid & 63, h = tid >> 6;
  const int quad = lane >> 4, l16 = lane & 15;
  const size_t wbase = (size_t)win * 49 * 768;

  // ---- Phase 1: S = (q*scale) @ k^T, padded to 64x64, K=32 (one MFMA/tile)
  b8 af[4], bfr[4];
#pragma unroll
  for (int ti = 0; ti < 4; ++ti) {
    const int tok = ti * 16 + l16;
    af[ti] = (tok < 49) ? *(const b8*)(qkv + wbase + (size_t)tok * 768 + h * 32 + quad * 8)
                        : zero_b8();
  }
#pragma unroll
  for (int tj = 0; tj < 4; ++tj) {
    const int key = tj * 16 + l16;
    bfr[tj] = (key < 49) ? *(const b8*)(qkv + wbase + (size_t)key * 768 + 256 + h * 32 + quad * 8)
                         : zero_b8();
  }
  f4 S[4][4];
#pragma unroll
  for (int ti = 0; ti < 4; ++ti)
#pragma unroll
    for (int tj = 0; tj < 4; ++tj) {
      S[ti][tj][0] = 0.f; S[ti][tj][1] = 0.f; S[ti][tj][2] = 0.f; S[ti][tj][3] = 0.f;
      S[ti][tj] = __builtin_amdgcn_mfma_f32_16x16x32_bf16(af[ti], bfr[tj], S[ti][tj], 0, 0, 0);
    }

  // ---- Phase 2: + precombined bias/mask table (coalesced L2 reads), row
  // softmax, P -> LDS bf16 with 16B-chunk XOR swizzle (chunk ^= row&7).
  ushort* P = sbuf + h * 4096;  // this head's 64x64
  const float* cmb = comb + ((((wh == 7) ? 2 : 0) + ((ww == 7) ? 1 : 0)) * 8 + h) * 4096;
#pragma unroll
  for (int ti = 0; ti < 4; ++ti) {
#pragma unroll
    for (int r = 0; r < 4; ++r) {
      const int i = ti * 16 + quad * 4 + r;
      const float* crow = cmb + i * 64 + l16;
      float sv[4];
#pragma unroll
      for (int tj = 0; tj < 4; ++tj) sv[tj] = S[ti][tj][r] + crow[tj * 16];
      float m = fmaxf(fmaxf(sv[0], sv[1]), fmaxf(sv[2], sv[3]));
#pragma unroll
      for (int d = 1; d < 16; d <<= 1) m = fmaxf(m, __shfl_xor(m, d));
      float sum = 0.f;
#pragma unroll
      for (int tj = 0; tj < 4; ++tj) { sv[tj] = __expf(sv[tj] - m); sum += sv[tj]; }
#pragma unroll
      for (int d = 1; d < 16; d <<= 1) sum += __shfl_xor(sum, d);
      const float inv = 1.f / sum;
      const int swz = i & 7, off = l16 & 7, cb = l16 >> 3;
#pragma unroll
      for (int tj = 0; tj < 4; ++tj) {
        const int cc = tj * 2 + cb;
        P[i * 64 + (((cc ^ swz) << 3) | off)] = f2bf(sv[tj] * inv);
      }
    }
  }

  // ---- Phase 3: O = P @ V (K=64 keys, 2 MFMAs per 16x16 out tile)
  f4 O[4][2];
#pragma unroll
  for (int ti = 0; ti < 4; ++ti)
#pragma unroll
    for (int tn = 0; tn < 2; ++tn) { O[ti][tn][0] = 0.f; O[ti][tn][1] = 0.f; O[ti][tn][2] = 0.f; O[ti][tn][3] = 0.f; }
#pragma unroll
  for (int kt = 0; kt < 2; ++kt) {
    b8 vb[2];
#pragma unroll
    for (int tn = 0; tn < 2; ++tn)
#pragma unroll
      for (int j = 0; j < 8; ++j) {
        const int key = kt * 32 + quad * 8 + j;  // B-frag: b[j]=V[k=quad*8+j][n=lane&15]
        vb[tn][j] = (key < 49)
            ? bfb(qkv[wbase + (size_t)key * 768 + 512 + h * 32 + tn * 16 + l16])
            : (__bf16)0.f;
      }
#pragma unroll
    for (int ti = 0; ti < 4; ++ti) {
      const int row = ti * 16 + l16;
      const b8 pa = *(const b8*)(P + row * 64 + (((kt * 4 + quad) ^ (row & 7)) << 3));
#pragma unroll
      for (int tn = 0; tn < 2; ++tn)
        O[ti][tn] = __builtin_amdgcn_mfma_f32_16x16x32_bf16(pa, vb[tn], O[ti][tn], 0, 0, 0);
    }
  }

  // ---- Phase 4: stage O (64 x 256 bf16) in LDS, XOR-swizzled (aliases P)
  __syncthreads();
  ushort* ob = sbuf;
#pragma unroll
  for (int ti = 0; ti < 4; ++ti)
#pragma unroll
    for (int tn = 0; tn < 2; ++tn)
#pragma unroll
      for (int r = 0; r < 4; ++r) {
        const int tok = ti * 16 + quad * 4 + r;
        const int cc = h * 4 + tn * 2 + (l16 >> 3);
        ob[tok * 256 + (((cc ^ (tok & 7)) << 3) | (l16 & 7))] = f2bf(O[ti][tn][r]);
      }
  __syncthreads();

  // ---- Phase 5: proj: (64x256) @ projw(256,256)^T; wave h owns 32 out cols
  f4 C[4][2];
#pragma unroll
  for (int ti = 0; ti < 4; ++ti)
#pragma unroll
    for (int tn = 0; tn < 2; ++tn) { C[ti][tn][0] = 0.f; C[ti][tn][1] = 0.f; C[ti][tn][2] = 0.f; C[ti][tn][3] = 0.f; }
  for (int k0 = 0; k0 < 256; k0 += 32) {
    b8 bw[2];
#pragma unroll
    for (int tn = 0; tn < 2; ++tn)
      bw[tn] = *(const b8*)(projw + (size_t)(h * 32 + tn * 16 + l16) * 256 + k0 + quad * 8);
#pragma unroll
    for (int ti = 0; ti < 4; ++ti) {
      const int row = ti * 16 + l16;
      const b8 pa = *(const b8*)(ob + row * 256 + ((((k0 >> 3) + quad) ^ (row & 7)) << 3));
#pragma unroll
      for (int tn = 0; tn < 2; ++tn)
        C[ti][tn] = __builtin_amdgcn_mfma_f32_16x16x32_bf16(pa, bw[tn], C[ti][tn], 0, 0, 0);
    }
  }

  // ---- Phase 6: stage proj output (64x256 fp32, 64KB) in LDS, float4-chunk
  // XOR swizzle (chunk ^= tok&7) to spread write banks.
  __syncthreads();  // all waves done reading ob
  float* fbuf = (float*)sbuf;
#pragma unroll
  for (int ti = 0; ti < 4; ++ti)
#pragma unroll
    for (int r = 0; r < 4; ++r) {
      const int tok = ti * 16 + quad * 4 + r;
      const int swz = tok & 7;
#pragma unroll
      for (int tn = 0; tn < 2; ++tn) {
        const int c4 = h * 8 + tn * 4 + (l16 >> 2);
        fbuf[tok * 256 + (((c4 ^ swz) << 2) | (l16 & 3))] = C[ti][tn][r];
      }
    }
  __syncthreads();

  // ---- Phase 7: per-token: x_after = proj + projb + shortcut (inverse
  // shift), store fp32; fused LN2 -> bf16 xw2 (raster token order).
  for (int t = h; t < 49; t += 8) {
    const int wy = t / 7, wx = t - wy * 7;
    int rr = wh * 7 + wy + 3; if (rr >= 56) rr -= 56;
    int cc = ww * 7 + wx + 3; if (cc >= 56) cc -= 56;
    const size_t base = ((size_t)b * 3136 + rr * 56 + cc) * 256;
    // swizzled read: location chunk lane^(t&7) holds column chunk `lane`
    float4 v = *(float4*)&fbuf[t * 256 + ((lane ^ (t & 7)) << 2)];
    const float4 pb = *(const float4*)(projb + lane * 4);
    const float4 xr = *(const float4*)(x_in + base + lane * 4);
    v.x += pb.x + xr.x; v.y += pb.y + xr.y; v.z += pb.z + xr.z; v.w += pb.w + xr.w;
    *(float4*)(x_out + base + lane * 4) = v;
    float s  = v.x + v.y + v.z + v.w;
    float s2 = v.x * v.x + v.y * v.y + v.z * v.z + v.w * v.w;
#pragma unroll
    for (int m = 32; m; m >>= 1) { s += __shfl_xor(s, m); s2 += __shfl_xor(s2, m); }
    const float mean = s * (1.f / 256.f);
    const float var  = s2 * (1.f / 256.f) - mean * mean;
    const float rs   = rsqrtf(var + 1e-5f);
    const float4 gv = *(const float4*)(n2g + lane * 4);
    const float4 bv = *(const float4*)(n2b + lane * 4);
    ushort4 o;
    o.x = f2bf((v.x - mean) * rs * gv.x + bv.x);
    o.y = f2bf((v.y - mean) * rs * gv.y + bv.y);
    o.z = f2bf((v.z - mean) * rs * gv.z + bv.z);
    o.w = f2bf((v.w - mean) * rs * gv.w + bv.w);
    *(ushort4*)(xw2 + base + lane * 4) = o;
  }
}

// ---------------------------------------------------------------------------
extern "C" void kernel_launch(void* const* d_in, const int* in_sizes, int n_in,
                              void* d_out, int out_size, void* d_ws, size_t ws_size,
                              hipStream_t stream) {
  const float* x     = (const float*)d_in[0];
  const float* n1g   = (const float*)d_in[1];
  const float* n1b   = (const float*)d_in[2];
  const float* qkvw  = (const float*)d_in[3];
  const float* qkvb  = (const float*)d_in[4];
  const float* relt  = (const float*)d_in[5];
  const float* projw = (const float*)d_in[6];
  const float* projb = (const float*)d_in[7];
  const float* n2g   = (const float*)d_in[8];
  const float* n2b   = (const float*)d_in[9];
  const float* fc1w  = (const float*)d_in[10];
  const float* fc1b  = (const float*)d_in[11];
  const float* fc2w  = (const float*)d_in[12];
  const float* fc2b  = (const float*)d_in[13];
  float* out = (float*)d_out;
  char* ws = (char*)d_ws;

  // ws layout:
  //   [0, 51.4MB)        xw: LN1 windowed bf16 A; reused as LN2 output (xw2)
  //   [51.4, 205.5MB)    qkv bf16 (154.1MB)
  //   [205.5, 206.0MB)   comb bias/mask table (512KB)
  //   [256.9, 258.5MB)   bf16 weights
  ushort* xw     = (ushort*)ws;
  ushort* qkv    = (ushort*)(ws + 51380224);
  float*  comb   = (float*)(ws + 205520896);   // after qkv's 154,140,672 bytes
  ushort* wqkv   = (ushort*)(ws + 51380224 + 205520896);
  ushort* wproj  = wqkv + 196608;
  ushort* wfc1   = wproj + 65536;
  ushort* wfc2   = wfc1 + 262144;

  static bool attr_done = false;
  if (!attr_done) {
    attr_done = true;
    hipFuncSetAttribute(reinterpret_cast<const void*>(&mlp2),
                        hipFuncAttributeMaxDynamicSharedMemorySize, 131072);
  }

  cast_w<<<768, 256, 0, stream>>>(qkvw, wqkv, 196608, projw, wproj, 65536,
                                  fc1w, wfc1, 262144, fc2w, wfc2, 262144);
  build_bias<<<512, 256, 0, stream>>>(relt, comb);
  // LN1 + shift + window partition -> bf16
  ln_shift<<<25088, 256, 0, stream>>>(x, n1g, n1b, xw, 1);
  // qkv: (100352,256) @ (768,256)^T — 1D grid, XCD-chunked, NT=6
  gemm_bt<<<4704, 256, 0, stream>>>(xw, wqkv, 256, 6, QkvEpi{qkv, qkvb});
  // attention + proj + residual + inverse shift + LN2 -> d_out, xw (bf16)
  attn_proj<<<2048, 512, 0, stream>>>(qkv, comb, wproj, projb, x, n2g, n2b, out, xw);
  // fused MLP v2: out += fc2(gelu(fc1(LN2(x_after)))) — no hidden round-trip
  mlp2<<<1568, 512, 131072, stream>>>(xw, wfc1, fc1b, wfc2, fc2b, out);
}

// Round 12
// 617.752 us; speedup vs baseline: 1.2311x; 1.1301x over previous
//
#include <hip/hip_runtime.h>

// ---------------------------------------------------------------------------
// Swin block, MI355X bf16-MFMA implementation.
// Shapes: B=32, H=W=56, DIM=256, WS=7, SHIFT=3, NH=8, HD=32, N=49, nW=64,
// Bw=2048, tokens T=100352.
// R1: attn_proj: comb bias table + LDS XOR-swizzles (landed)
// R2: gemm_bt 128²: dbuf prefetch + XCD-chunked grid (landed: 678 µs)
// R3/R5/R6: schedule variants (NULL) / R4: mlp_fused v1 (REGRESSED)
// R7: __launch_bounds__(256,4) + VALU diet: 654 µs (prev best)
// R8: B-direct gathers (REGRESSED — 16-lane row-stride gather on MFMA chain)
// R9: wave-autonomous (REGRESSED) / R10: mlp2 race (FAILED) / R11: fixed,
//     passes, but 336 µs — traffic great (FETCH 92MB), stalled on the SAME
//     R8 gather pattern in the W1/W2 fragment reads.
// R12: FRAGMENT-MAJOR WEIGHTS for mlp2: pre-pack W1/W2 at cast time so each
//     MFMA B-fragment is a coalesced base+lane*16B wave-read (the gload_lds
//     source pattern) instead of a 16-line L2 gather. mlp2 loop structure
//     identical to R11 (which passed); only weight addressing changes.
// ---------------------------------------------------------------------------

typedef float f4 __attribute__((ext_vector_type(4)));
typedef __bf16 b8 __attribute__((ext_vector_type(8)));

#define DEV static __device__ __forceinline__

DEV ushort f2bf(float f) {
  union { __bf16 b; ushort u; } c; c.b = (__bf16)f;   // HW v_cvt, RNE
  return c.u;
}
DEV __bf16 bfb(ushort u) { union { ushort u; __bf16 b; } c; c.u = u; return c.b; }
DEV b8 zero_b8() {
  b8 z;
#pragma unroll
  for (int i = 0; i < 8; ++i) z[i] = (__bf16)0.f;
  return z;
}
DEV void load_lds16(const void* g, void* l) {
  // lane i's 16B land at ldsbase + i*16 (wave-uniform base) [m97/m104]
  __builtin_amdgcn_global_load_lds(
      (const __attribute__((address_space(1))) unsigned int*)g,
      (__attribute__((address_space(3))) unsigned int*)l, 16, 0, 0);
}
DEV int reg3(int t) { return t < 49 ? 0 : (t < 53 ? 1 : 2); }  // shift-mask region row/col id

// ---------------------------------------------------------------------------
// weights fp32 -> bf16 (row-major: qkv + proj, consumed via gload_lds / LDS)
__global__ __launch_bounds__(256) void cast_w(const float* a, ushort* oa, int na,
                                              const float* b, ushort* ob, int nb) {
  int total = na + nb;
  for (int i = blockIdx.x * 256 + threadIdx.x; i < total; i += gridDim.x * 256) {
    int j = i;
    if (j < na) { oa[j] = f2bf(a[j]); continue; }
    j -= na;
    ob[j] = f2bf(b[j]);
  }
}

// ---------------------------------------------------------------------------
// weights fp32 -> bf16 FRAGMENT-MAJOR: element (col=ct*16+l16,
// k=kc*32+quad*8+j) of W[N][K] stored at ((ct*K32+kc)*64 + lane)*8 + j,
// lane = quad*16+l16. A wave's b8 fragment read becomes base + lane*16B
// (coalesced 1KB), replacing a 16-line row-stride gather.
__global__ __launch_bounds__(256) void cast_frag(const float* __restrict__ w,
                                                 ushort* __restrict__ wf, int K32) {
  const int o = blockIdx.x * 256 + threadIdx.x;   // grid sized exactly N*K
  const int q = o & 511;
  const int j = q & 7, l16 = (q >> 3) & 15, quad = q >> 7;
  const int t = o >> 9;
  const int kc = t % K32, ct = t / K32;
  const int K = K32 << 5;
  wf[o] = f2bf(w[(size_t)(ct * 16 + l16) * K + kc * 32 + quad * 8 + j]);
}

// ---------------------------------------------------------------------------
// comb[type][h][i][j]: rel-pos bias + shift mask + pad (-1e30), fp32.
// type = (wh==7)*2 + (ww==7) — only 4 distinct window mask patterns exist.
__global__ __launch_bounds__(256) void build_bias(const float* __restrict__ rel_table,
                                                  float* __restrict__ comb) {
  const int idx = blockIdx.x * 256 + threadIdx.x;  // 4*8*64*64 = 131072
  if (idx >= 4 * 8 * 64 * 64) return;
  const int j = idx & 63, i = (idx >> 6) & 63, h = (idx >> 12) & 7, ty = idx >> 15;
  float v;
  if (i < 49 && j < 49) {
    const int iy = i / 7, ix = i - iy * 7, jy = j / 7, jx = j - jy * 7;
    const int ridx = (iy - jy + 6) * 13 + (ix - jx + 6);
    v = rel_table[ridx * 8 + h];
    const int wh = (ty & 2) ? 7 : 0, ww = (ty & 1) ? 7 : 0;
    const int irg = reg3(wh * 7 + iy) * 3 + reg3(ww * 7 + ix);
    const int jrg = reg3(wh * 7 + jy) * 3 + reg3(ww * 7 + jx);
    if (irg != jrg) v -= 100.f;
  } else {
    v = -1e30f;  // padding: exp(-inf) = 0 for j>=49; rows i>=49 harmless
  }
  comb[idx] = v;
}

// ---------------------------------------------------------------------------
// LayerNorm over 256 ch, one wave per token; optional (-3,-3) cyclic shift +
// window partition on the output index. out: bf16 (token, 256) row-major.
__global__ __launch_bounds__(256) void ln_shift(const float* __restrict__ x,
                                                const float* __restrict__ g,
                                                const float* __restrict__ bta,
                                                ushort* __restrict__ out, int shifted) {
  const int wid = threadIdx.x >> 6, lane = threadIdx.x & 63;
  const int t = blockIdx.x * 4 + wid;           // output token (windowed order if shifted)
  int src;
  if (shifted) {
    int win = t / 49, n = t - win * 49;
    int bb = win >> 6, wh = (win >> 3) & 7, ww = win & 7;
    int wy = n / 7, wx = n - wy * 7;
    int r = wh * 7 + wy + 3; if (r >= 56) r -= 56;
    int c = ww * 7 + wx + 3; if (c >= 56) c -= 56;
    src = bb * 3136 + r * 56 + c;
  } else {
    src = t;
  }
  const float4 v = *(const float4*)(x + (size_t)src * 256 + lane * 4);
  float s  = v.x + v.y + v.z + v.w;
  float s2 = v.x * v.x + v.y * v.y + v.z * v.z + v.w * v.w;
#pragma unroll
  for (int m = 32; m; m >>= 1) { s += __shfl_xor(s, m); s2 += __shfl_xor(s2, m); }
  const float mean = s * (1.f / 256.f);
  const float var  = s2 * (1.f / 256.f) - mean * mean;
  const float rs   = rsqrtf(var + 1e-5f);
  const float4 gv = *(const float4*)(g + lane * 4);
  const float4 bv = *(const float4*)(bta + lane * 4);
  ushort4 o;
  o.x = f2bf((v.x - mean) * rs * gv.x + bv.x);
  o.y = f2bf((v.y - mean) * rs * gv.y + bv.y);
  o.z = f2bf((v.z - mean) * rs * gv.z + bv.z);
  o.w = f2bf((v.w - mean) * rs * gv.w + bv.w);
  *(ushort4*)(out + (size_t)t * 256 + lane * 4) = o;
}

// ---------------------------------------------------------------------------
// Generic bf16 GEMM (R7 form, 654 µs config): C[M,N] = A[M,K] @ B[N,K]^T,
// 128x128 tile, BK=32, 256 thr (2x2 waves), gload_lds staging, dbuf.
// __launch_bounds__(256,4) -> 4 blocks/CU.
template <class Epi>
__global__ __launch_bounds__(256, 4) void gemm_bt(const ushort* __restrict__ A,
                                                  const ushort* __restrict__ B,
                                                  int K, int NT, Epi epi) {
  __shared__ ushort lsA[2][128 * 32];
  __shared__ ushort lsB[2][128 * 32];
  const int tid = threadIdx.x;
  const int lane = tid & 63, wid = tid >> 6;
  const int quad = lane >> 4, l16 = lane & 15;
  const int wm = wid >> 1, wn = wid & 1;
  // XCD-chunked bijective remap (nwg = 784*NT, divisible by 8)
  const int lin = blockIdx.x;
  const int xcd = lin & 7, j = lin >> 3;
  const int mt = xcd * 98 + j / NT;            // 98 = 784/8 stripes per XCD
  const int nt_ = j % NT;
  const long rowA0 = (long)mt * 128;
  const long colB0 = (long)nt_ * 128;
  f4 acc[4][4];
#pragma unroll
  for (int i = 0; i < 4; ++i)
#pragma unroll
    for (int jj = 0; jj < 4; ++jj) { acc[i][jj][0] = 0.f; acc[i][jj][1] = 0.f; acc[i][jj][2] = 0.f; acc[i][jj][3] = 0.f; }
  const int lrow = lane >> 2;
  const int lk = ((lane & 3) ^ ((lane >> 3) & 3)) * 8;   // swizzled global k-chunk
  const int rsw = (quad ^ ((l16 >> 1) & 3)) * 8;         // swizzled read slot
  const int seg0 = wid * 2, seg1 = wid * 2 + 1;
  const ushort* pa0 = A + (rowA0 + seg0 * 16 + lrow) * (long)K + lk;
  const ushort* pa1 = A + (rowA0 + seg1 * 16 + lrow) * (long)K + lk;
  const ushort* pb0 = B + (colB0 + seg0 * 16 + lrow) * (long)K + lk;
  const ushort* pb1 = B + (colB0 + seg1 * 16 + lrow) * (long)K + lk;

  const int nsteps = K >> 5;
  load_lds16(pa0, &lsA[0][seg0 * 512]);
  load_lds16(pa1, &lsA[0][seg1 * 512]);
  load_lds16(pb0, &lsB[0][seg0 * 512]);
  load_lds16(pb1, &lsB[0][seg1 * 512]);
  __syncthreads();

  for (int t = 0; t < nsteps; ++t) {
    const int cur = t & 1;
    if (t + 1 < nsteps) {
      const int k1 = (t + 1) << 5;
      load_lds16(pa0 + k1, &lsA[cur ^ 1][seg0 * 512]);
      load_lds16(pa1 + k1, &lsA[cur ^ 1][seg1 * 512]);
      load_lds16(pb0 + k1, &lsB[cur ^ 1][seg0 * 512]);
      load_lds16(pb1 + k1, &lsB[cur ^ 1][seg1 * 512]);
    }
    b8 af[4], bfr[4];
#pragma unroll
    for (int ti = 0; ti < 4; ++ti)
      af[ti] = *(const b8*)&lsA[cur][(wm * 64 + ti * 16 + l16) * 32 + rsw];
#pragma unroll
    for (int tj = 0; tj < 4; ++tj)
      bfr[tj] = *(const b8*)&lsB[cur][(wn * 64 + tj * 16 + l16) * 32 + rsw];
#pragma unroll
    for (int ti = 0; ti < 4; ++ti)
#pragma unroll
      for (int tj = 0; tj < 4; ++tj)
        acc[ti][tj] = __builtin_amdgcn_mfma_f32_16x16x32_bf16(af[ti], bfr[tj], acc[ti][tj], 0, 0, 0);
    __syncthreads();
  }
  // C/D layout: row = quad*4+reg, col = lane&15 [m89/m91]
#pragma unroll
  for (int ti = 0; ti < 4; ++ti)
#pragma unroll
    for (int tj = 0; tj < 4; ++tj)
#pragma unroll
      for (int r = 0; r < 4; ++r)
        epi((int)(rowA0 + wm * 64 + ti * 16 + quad * 4 + r),
            (int)(colB0 + wn * 64 + tj * 16 + l16), acc[ti][tj][r]);
}

struct QkvEpi {
  ushort* out; const float* bias;
  __device__ void operator()(int r, int c, float v) const {
    v += bias[c];
    if (c < 256) v *= 0.17677669529663687f;  // HD^-0.5, pre-scale q
    out[(size_t)r * 768 + c] = f2bf(v);
  }
};

// ---------------------------------------------------------------------------
// Fused MLP v3: out += fc2(gelu(fc1(xw2)+b1))+b2 per 64-token stripe.
// 512 thr / 8 waves. LDS 128KB: A (32KB, gemm staging layout) at ls[0];
// H (64x1024 bf16, XOR-swizzled, 128KB) aliases it after a barrier.
// W1/W2 are FRAGMENT-MAJOR (cast_frag): every b8 fragment load is
// base + lane*16B — coalesced 1KB wave-read, no gathers (R12).
// fc1: wave h owns H cols [h*128,+128), K=256 unrolled, no barriers inside.
// fc2: wave h owns out cols [h*32,+32), K=1024. 3 barriers per block.
__global__ __launch_bounds__(512, 2) void mlp2(const ushort* __restrict__ A,
                                               const ushort* __restrict__ w1f,
                                               const float* __restrict__ b1,
                                               const ushort* __restrict__ w2f,
                                               const float* __restrict__ b2,
                                               float* __restrict__ out) {
  extern __shared__ __align__(16) ushort ls[];   // 128KB
  ushort* lsA = ls;          // [0, 16384) ushorts = 32KB, dead after fc1
  ushort* lsH = ls;          // [0, 65536) ushorts = 128KB, written after bar
  const int tid = threadIdx.x, lane = tid & 63, h = tid >> 6;
  const int quad = lane >> 4, l16 = lane & 15;
  const long r0 = (long)blockIdx.x * 64;
  const int lrow = lane >> 2;
  const int lk = ((lane & 3) ^ ((lane >> 3) & 3)) * 8;   // swizzled global k-chunk
  const int rsw = (quad ^ ((l16 >> 1) & 3)) * 8;         // swizzled read slot
  // fragment-major weight bases: wave h's slice, per-lane 16B (coalesced)
  const ushort* w1b = w1f + ((size_t)h << 15) + lane * 8;  // (h*8 ct)*8 kc*512
  const ushort* w2b = w2f + ((size_t)h << 15) + lane * 8;  // (h*2 ct)*32 kc*512

  // ---- stage A (64x256, 32KB): wave h stages k-chunk h (4 segments x 1KB)
#pragma unroll
  for (int seg = 0; seg < 4; ++seg)
    load_lds16(A + (r0 + seg * 16 + lrow) * 256 + h * 32 + lk,
               &lsA[h * 2048 + seg * 512]);
  __syncthreads();   // A resident block-wide (barrier drains vmcnt)

  // ---- fc1: acc1[4][8] = A @ W1^T for cols [h*128, +128), K=256 unrolled
  f4 a1[4][8];
#pragma unroll
  for (int ti = 0; ti < 4; ++ti)
#pragma unroll
    for (int tn = 0; tn < 8; ++tn) { a1[ti][tn][0] = 0.f; a1[ti][tn][1] = 0.f; a1[ti][tn][2] = 0.f; a1[ti][tn][3] = 0.f; }
#pragma unroll
  for (int kc = 0; kc < 8; ++kc) {
    b8 bw[8];
#pragma unroll
    for (int tn = 0; tn < 8; ++tn)
      bw[tn] = *(const b8*)(w1b + ((tn * 8 + kc) << 9));
    b8 af[4];
#pragma unroll
    for (int ti = 0; ti < 4; ++ti)
      af[ti] = *(const b8*)&lsA[kc * 2048 + (ti * 16 + l16) * 32 + rsw];
#pragma unroll
    for (int ti = 0; ti < 4; ++ti)
#pragma unroll
      for (int tn = 0; tn < 8; ++tn)
        a1[ti][tn] = __builtin_amdgcn_mfma_f32_16x16x32_bf16(af[ti], bw[tn], a1[ti][tn], 0, 0, 0);
  }
  __syncthreads();   // ALL waves done reading A before H overwrites it

  // ---- bias + exact gelu -> H (16B-chunk XOR swizzle: cc ^= row&7)
  float b1v[8];
#pragma unroll
  for (int tn = 0; tn < 8; ++tn) b1v[tn] = b1[h * 128 + tn * 16 + l16];
#pragma unroll
  for (int ti = 0; ti < 4; ++ti)
#pragma unroll
    for (int tn = 0; tn < 8; ++tn)
#pragma unroll
      for (int rr = 0; rr < 4; ++rr) {
        const int row = ti * 16 + quad * 4 + rr;
        const int cc = h * 16 + tn * 2 + (l16 >> 3);   // 16B chunk of col
        float v = a1[ti][tn][rr] + b1v[tn];
        v = 0.5f * v * (1.f + erff(v * 0.70710678118654752f));
        lsH[row * 1024 + (((cc ^ (row & 7)) << 3) | (l16 & 7))] = f2bf(v);
      }
  __syncthreads();   // H visible block-wide

  // ---- fc2: acc2[4][2] = H @ W2^T for cols [h*32, +32), K=1024
  f4 a2[4][2];
#pragma unroll
  for (int ti = 0; ti < 4; ++ti)
#pragma unroll
    for (int tn = 0; tn < 2; ++tn) { a2[ti][tn][0] = 0.f; a2[ti][tn][1] = 0.f; a2[ti][tn][2] = 0.f; a2[ti][tn][3] = 0.f; }
#pragma unroll 8
  for (int kc = 0; kc < 32; ++kc) {
    b8 bw2[2];
#pragma unroll
    for (int tn = 0; tn < 2; ++tn)
      bw2[tn] = *(const b8*)(w2b + ((tn * 32 + kc) << 9));
#pragma unroll
    for (int ti = 0; ti < 4; ++ti) {
      const int row = ti * 16 + l16;
      const b8 pa = *(const b8*)&lsH[row * 1024 + ((((kc * 4 + quad)) ^ (row & 7)) << 3)];
#pragma unroll
      for (int tn = 0; tn < 2; ++tn)
        a2[ti][tn] = __builtin_amdgcn_mfma_f32_16x16x32_bf16(pa, bw2[tn], a2[ti][tn], 0, 0, 0);
    }
  }

  // ---- epilogue: out += C + b2
#pragma unroll
  for (int tn = 0; tn < 2; ++tn) {
    const float bb = b2[h * 32 + tn * 16 + l16];
#pragma unroll
    for (int ti = 0; ti < 4; ++ti)
#pragma unroll
      for (int rr = 0; rr < 4; ++rr) {
        const size_t i = (size_t)(r0 + ti * 16 + quad * 4 + rr) * 256 + h * 32 + tn * 16 + l16;
        out[i] += a2[ti][tn][rr] + bb;
      }
  }
}

// ---------------------------------------------------------------------------
// Attention + proj + residual + LN2, one block per window (512 thr), one
// wave/head. qkv rows: [q(256, pre-scaled) | k(256) | v(256)] bf16.
// Writes x_after (fp32, d_out) and LN2(x_after) (bf16, fc1's A) directly.
__global__ __launch_bounds__(512) void attn_proj(const ushort* __restrict__ qkv,
                                                 const float* __restrict__ comb,
                                                 const ushort* __restrict__ projw,
                                                 const float* __restrict__ projb,
                                                 const float* __restrict__ x_in,
                                                 const float* __restrict__ n2g,
                                                 const float* __restrict__ n2b,
                                                 float* __restrict__ x_out,
                                                 ushort* __restrict__ xw2) {
  __shared__ ushort sbuf[32768];  // 64KB: P (8 x 64x64) ; O staging ; fp32 x_after
  const int win = blockIdx.x;
  const int b = win >> 6, wh = (win >> 3) & 7, ww = win & 7;
  const int tid = threadIdx.x, lane = tid & 63, h = tid >> 6;
  const int quad = lane >> 4, l16 = lane & 15;
  const size_t wbase = (size_t)win * 49 * 768;

  // ---- Phase 1: S = (q*scale) @ k^T, padded to 64x64, K=32 (one MFMA/tile)
  b8 af[4], bfr[4];
#pragma unroll
  for (int ti = 0; ti < 4; ++ti) {
    const int tok = ti * 16 + l16;
    af[ti] = (tok < 49) ? *(const b8*)(qkv + wbase + (size_t)tok * 768 + h * 32 + quad * 8)
                        : zero_b8();
  }
#pragma unroll
  for (int tj = 0; tj < 4; ++tj) {
    const int key = tj * 16 + l16;
    bfr[tj] = (key < 49) ? *(const b8*)(qkv + wbase + (size_t)key * 768 + 256 + h * 32 + quad * 8)
                         : zero_b8();
  }
  f4 S[4][4];
#pragma unroll
  for (int ti = 0; ti < 4; ++ti)
#pragma unroll
    for (int tj = 0; tj < 4; ++tj) {
      S[ti][tj][0] = 0.f; S[ti][tj][1] = 0.f; S[ti][tj][2] = 0.f; S[ti][tj][3] = 0.f;
      S[ti][tj] = __builtin_amdgcn_mfma_f32_16x16x32_bf16(af[ti], bfr[tj], S[ti][tj], 0, 0, 0);
    }

  // ---- Phase 2: + precombined bias/mask table (coalesced L2 reads), row
  // softmax, P -> LDS bf16 with 16B-chunk XOR swizzle (chunk ^= row&7).
  ushort* P = sbuf + h * 4096;  // this head's 64x64
  const float* cmb = comb + ((((wh == 7) ? 2 : 0) + ((ww == 7) ? 1 : 0)) * 8 + h) * 4096;
#pragma unroll
  for (int ti = 0; ti < 4; ++ti) {
#pragma unroll
    for (int r = 0; r < 4; ++r) {
      const int i = ti * 16 + quad * 4 + r;
      const float* crow = cmb + i * 64 + l16;
      float sv[4];
#pragma unroll
      for (int tj = 0; tj < 4; ++tj) sv[tj] = S[ti][tj][r] + crow[tj * 16];
      float m = fmaxf(fmaxf(sv[0], sv[1]), fmaxf(sv[2], sv[3]));
#pragma unroll
      for (int d = 1; d < 16; d <<= 1) m = fmaxf(m, __shfl_xor(m, d));
      float sum = 0.f;
#pragma unroll
      for (int tj = 0; tj < 4; ++tj) { sv[tj] = __expf(sv[tj] - m); sum += sv[tj]; }
#pragma unroll
      for (int d = 1; d < 16; d <<= 1) sum += __shfl_xor(sum, d);
      const float inv = 1.f / sum;
      const int swz = i & 7, off = l16 & 7, cb = l16 >> 3;
#pragma unroll
      for (int tj = 0; tj < 4; ++tj) {
        const int cc = tj * 2 + cb;
        P[i * 64 + (((cc ^ swz) << 3) | off)] = f2bf(sv[tj] * inv);
      }
    }
  }

  // ---- Phase 3: O = P @ V (K=64 keys, 2 MFMAs per 16x16 out tile)
  f4 O[4][2];
#pragma unroll
  for (int ti = 0; ti < 4; ++ti)
#pragma unroll
    for (int tn = 0; tn < 2; ++tn) { O[ti][tn][0] = 0.f; O[ti][tn][1] = 0.f; O[ti][tn][2] = 0.f; O[ti][tn][3] = 0.f; }
#pragma unroll
  for (int kt = 0; kt < 2; ++kt) {
    b8 vb[2];
#pragma unroll
    for (int tn = 0; tn < 2; ++tn)
#pragma unroll
      for (int j = 0; j < 8; ++j) {
        const int key = kt * 32 + quad * 8 + j;  // B-frag: b[j]=V[k=quad*8+j][n=lane&15]
        vb[tn][j] = (key < 49)
            ? bfb(qkv[wbase + (size_t)key * 768 + 512 + h * 32 + tn * 16 + l16])
            : (__bf16)0.f;
      }
#pragma unroll
    for (int ti = 0; ti < 4; ++ti) {
      const int row = ti * 16 + l16;
      const b8 pa = *(const b8*)(P + row * 64 + (((kt * 4 + quad) ^ (row & 7)) << 3));
#pragma unroll
      for (int tn = 0; tn < 2; ++tn)
        O[ti][tn] = __builtin_amdgcn_mfma_f32_16x16x32_bf16(pa, vb[tn], O[ti][tn], 0, 0, 0);
    }
  }

  // ---- Phase 4: stage O (64 x 256 bf16) in LDS, XOR-swizzled (aliases P)
  __syncthreads();
  ushort* ob = sbuf;
#pragma unroll
  for (int ti = 0; ti < 4; ++ti)
#pragma unroll
    for (int tn = 0; tn < 2; ++tn)
#pragma unroll
      for (int r = 0; r < 4; ++r) {
        const int tok = ti * 16 + quad * 4 + r;
        const int cc = h * 4 + tn * 2 + (l16 >> 3);
        ob[tok * 256 + (((cc ^ (tok & 7)) << 3) | (l16 & 7))] = f2bf(O[ti][tn][r]);
      }
  __syncthreads();

  // ---- Phase 5: proj: (64x256) @ projw(256,256)^T; wave h owns 32 out cols
  f4 C[4][2];
#pragma unroll
  for (int ti = 0; ti < 4; ++ti)
#pragma unroll
    for (int tn = 0; tn < 2; ++tn) { C[ti][tn][0] = 0.f; C[ti][tn][1] = 0.f; C[ti][tn][2] = 0.f; C[ti][tn][3] = 0.f; }
  for (int k0 = 0; k0 < 256; k0 += 32) {
    b8 bw[2];
#pragma unroll
    for (int tn = 0; tn < 2; ++tn)
      bw[tn] = *(const b8*)(projw + (size_t)(h * 32 + tn * 16 + l16) * 256 + k0 + quad * 8);
#pragma unroll
    for (int ti = 0; ti < 4; ++ti) {
      const int row = ti * 16 + l16;
      const b8 pa = *(const b8*)(ob + row * 256 + ((((k0 >> 3) + quad) ^ (row & 7)) << 3));
#pragma unroll
      for (int tn = 0; tn < 2; ++tn)
        C[ti][tn] = __builtin_amdgcn_mfma_f32_16x16x32_bf16(pa, bw[tn], C[ti][tn], 0, 0, 0);
    }
  }

  // ---- Phase 6: stage proj output (64x256 fp32, 64KB) in LDS, float4-chunk
  // XOR swizzle (chunk ^= tok&7) to spread write banks.
  __syncthreads();  // all waves done reading ob
  float* fbuf = (float*)sbuf;
#pragma unroll
  for (int ti = 0; ti < 4; ++ti)
#pragma unroll
    for (int r = 0; r < 4; ++r) {
      const int tok = ti * 16 + quad * 4 + r;
      const int swz = tok & 7;
#pragma unroll
      for (int tn = 0; tn < 2; ++tn) {
        const int c4 = h * 8 + tn * 4 + (l16 >> 2);
        fbuf[tok * 256 + (((c4 ^ swz) << 2) | (l16 & 3))] = C[ti][tn][r];
      }
    }
  __syncthreads();

  // ---- Phase 7: per-token: x_after = proj + projb + shortcut (inverse
  // shift), store fp32; fused LN2 -> bf16 xw2 (raster token order).
  for (int t = h; t < 49; t += 8) {
    const int wy = t / 7, wx = t - wy * 7;
    int rr = wh * 7 + wy + 3; if (rr >= 56) rr -= 56;
    int cc = ww * 7 + wx + 3; if (cc >= 56) cc -= 56;
    const size_t base = ((size_t)b * 3136 + rr * 56 + cc) * 256;
    // swizzled read: location chunk lane^(t&7) holds column chunk `lane`
    float4 v = *(float4*)&fbuf[t * 256 + ((lane ^ (t & 7)) << 2)];
    const float4 pb = *(const float4*)(projb + lane * 4);
    const float4 xr = *(const float4*)(x_in + base + lane * 4);
    v.x += pb.x + xr.x; v.y += pb.y + xr.y; v.z += pb.z + xr.z; v.w += pb.w + xr.w;
    *(float4*)(x_out + base + lane * 4) = v;
    float s  = v.x + v.y + v.z + v.w;
    float s2 = v.x * v.x + v.y * v.y + v.z * v.z + v.w * v.w;
#pragma unroll
    for (int m = 32; m; m >>= 1) { s += __shfl_xor(s, m); s2 += __shfl_xor(s2, m); }
    const float mean = s * (1.f / 256.f);
    const float var  = s2 * (1.f / 256.f) - mean * mean;
    const float rs   = rsqrtf(var + 1e-5f);
    const float4 gv = *(const float4*)(n2g + lane * 4);
    const float4 bv = *(const float4*)(n2b + lane * 4);
    ushort4 o;
    o.x = f2bf((v.x - mean) * rs * gv.x + bv.x);
    o.y = f2bf((v.y - mean) * rs * gv.y + bv.y);
    o.z = f2bf((v.z - mean) * rs * gv.z + bv.z);
    o.w = f2bf((v.w - mean) * rs * gv.w + bv.w);
    *(ushort4*)(xw2 + base + lane * 4) = o;
  }
}

// ---------------------------------------------------------------------------
extern "C" void kernel_launch(void* const* d_in, const int* in_sizes, int n_in,
                              void* d_out, int out_size, void* d_ws, size_t ws_size,
                              hipStream_t stream) {
  const float* x     = (const float*)d_in[0];
  const float* n1g   = (const float*)d_in[1];
  const float* n1b   = (const float*)d_in[2];
  const float* qkvw  = (const float*)d_in[3];
  const float* qkvb  = (const float*)d_in[4];
  const float* relt  = (const float*)d_in[5];
  const float* projw = (const float*)d_in[6];
  const float* projb = (const float*)d_in[7];
  const float* n2g   = (const float*)d_in[8];
  const float* n2b   = (const float*)d_in[9];
  const float* fc1w  = (const float*)d_in[10];
  const float* fc1b  = (const float*)d_in[11];
  const float* fc2w  = (const float*)d_in[12];
  const float* fc2b  = (const float*)d_in[13];
  float* out = (float*)d_out;
  char* ws = (char*)d_ws;

  // ws layout:
  //   [0, 51.4MB)        xw: LN1 windowed bf16 A; reused as LN2 output (xw2)
  //   [51.4, 205.5MB)    qkv bf16 (154.1MB)
  //   [205.5, 206.0MB)   comb bias/mask table (512KB)
  //   [256.9, 258.5MB)   bf16 weights (wqkv, wproj row-major; wfc1/wfc2
  //                      fragment-major for mlp2)
  ushort* xw     = (ushort*)ws;
  ushort* qkv    = (ushort*)(ws + 51380224);
  float*  comb   = (float*)(ws + 205520896);   // after qkv's 154,140,672 bytes
  ushort* wqkv   = (ushort*)(ws + 51380224 + 205520896);
  ushort* wproj  = wqkv + 196608;
  ushort* wfc1   = wproj + 65536;    // fragment-major (1024x256, K32=8)
  ushort* wfc2   = wfc1 + 262144;    // fragment-major (256x1024, K32=32)

  static bool attr_done = false;
  if (!attr_done) {
    attr_done = true;
    hipFuncSetAttribute(reinterpret_cast<const void*>(&mlp2),
                        hipFuncAttributeMaxDynamicSharedMemorySize, 131072);
  }

  cast_w<<<512, 256, 0, stream>>>(qkvw, wqkv, 196608, projw, wproj, 65536);
  cast_frag<<<1024, 256, 0, stream>>>(fc1w, wfc1, 8);    // 1024x256
  cast_frag<<<1024, 256, 0, stream>>>(fc2w, wfc2, 32);   // 256x1024
  build_bias<<<512, 256, 0, stream>>>(relt, comb);
  // LN1 + shift + window partition -> bf16
  ln_shift<<<25088, 256, 0, stream>>>(x, n1g, n1b, xw, 1);
  // qkv: (100352,256) @ (768,256)^T — 1D grid, XCD-chunked, NT=6
  gemm_bt<<<4704, 256, 0, stream>>>(xw, wqkv, 256, 6, QkvEpi{qkv, qkvb});
  // attention + proj + residual + inverse shift + LN2 -> d_out, xw (bf16)
  attn_proj<<<2048, 512, 0, stream>>>(qkv, comb, wproj, projb, x, n2g, n2b, out, xw);
  // fused MLP v3 (fragment-major weights): out += fc2(gelu(fc1(xw2)))
  mlp2<<<1568, 512, 131072, stream>>>(xw, wfc1, fc1b, wfc2, fc2b, out);
}

// Round 13
// 584.150 us; speedup vs baseline: 1.3019x; 1.0575x over previous
//
#include <hip/hip_runtime.h>

// ---------------------------------------------------------------------------
// Swin block, MI355X bf16-MFMA implementation.
// Shapes: B=32, H=W=56, DIM=256, WS=7, SHIFT=3, NH=8, HD=32, N=49, nW=64,
// Bw=2048, tokens T=100352.
// R1: attn_proj: comb bias table + LDS XOR-swizzles (landed)
// R2: gemm_bt 128²: dbuf prefetch + XCD-chunked grid (landed: 678 µs)
// R3/R5/R6: schedule variants (NULL) / R4: mlp_fused v1 (REGRESSED)
// R7: __launch_bounds__(256,4) + VALU diet: 654 µs
// R8: B-direct gathers (REGRESSED) / R9: wave-autonomous (REGRESSED)
// R10/R11: mlp2 fusion (race -> fixed, 336 µs; gathers remained)
// R12: FRAGMENT-MAJOR weights: mlp2 336 -> 247, total 617.8 µs (best)
// R13: mlp2 occupancy: 32-token stripes (H=64KB LDS) -> 2 blocks/CU,
//      4 waves/SIMD (was 1 block, 2 waves/SIMD at 128KB). Halved
//      accumulators; fc1 weight loads in 2 groups of 4 to fit 128 regs.
//      Cost: weight L2 traffic x2 (~3.2GB, ~93µs aggregate) — overlappable.
// ---------------------------------------------------------------------------

typedef float f4 __attribute__((ext_vector_type(4)));
typedef __bf16 b8 __attribute__((ext_vector_type(8)));

#define DEV static __device__ __forceinline__

DEV ushort f2bf(float f) {
  union { __bf16 b; ushort u; } c; c.b = (__bf16)f;   // HW v_cvt, RNE
  return c.u;
}
DEV __bf16 bfb(ushort u) { union { ushort u; __bf16 b; } c; c.u = u; return c.b; }
DEV b8 zero_b8() {
  b8 z;
#pragma unroll
  for (int i = 0; i < 8; ++i) z[i] = (__bf16)0.f;
  return z;
}
DEV void load_lds16(const void* g, void* l) {
  // lane i's 16B land at ldsbase + i*16 (wave-uniform base) [m97/m104]
  __builtin_amdgcn_global_load_lds(
      (const __attribute__((address_space(1))) unsigned int*)g,
      (__attribute__((address_space(3))) unsigned int*)l, 16, 0, 0);
}
DEV int reg3(int t) { return t < 49 ? 0 : (t < 53 ? 1 : 2); }  // shift-mask region row/col id

// ---------------------------------------------------------------------------
// weights fp32 -> bf16 (row-major: qkv + proj, consumed via gload_lds / LDS)
__global__ __launch_bounds__(256) void cast_w(const float* a, ushort* oa, int na,
                                              const float* b, ushort* ob, int nb) {
  int total = na + nb;
  for (int i = blockIdx.x * 256 + threadIdx.x; i < total; i += gridDim.x * 256) {
    int j = i;
    if (j < na) { oa[j] = f2bf(a[j]); continue; }
    j -= na;
    ob[j] = f2bf(b[j]);
  }
}

// ---------------------------------------------------------------------------
// weights fp32 -> bf16 FRAGMENT-MAJOR: element (col=ct*16+l16,
// k=kc*32+quad*8+j) of W[N][K] stored at ((ct*K32+kc)*64 + lane)*8 + j,
// lane = quad*16+l16. A wave's b8 fragment read becomes base + lane*16B
// (coalesced 1KB), replacing a 16-line row-stride gather.
__global__ __launch_bounds__(256) void cast_frag(const float* __restrict__ w,
                                                 ushort* __restrict__ wf, int K32) {
  const int o = blockIdx.x * 256 + threadIdx.x;   // grid sized exactly N*K
  const int q = o & 511;
  const int j = q & 7, l16 = (q >> 3) & 15, quad = q >> 7;
  const int t = o >> 9;
  const int kc = t % K32, ct = t / K32;
  const int K = K32 << 5;
  wf[o] = f2bf(w[(size_t)(ct * 16 + l16) * K + kc * 32 + quad * 8 + j]);
}

// ---------------------------------------------------------------------------
// comb[type][h][i][j]: rel-pos bias + shift mask + pad (-1e30), fp32.
// type = (wh==7)*2 + (ww==7) — only 4 distinct window mask patterns exist.
__global__ __launch_bounds__(256) void build_bias(const float* __restrict__ rel_table,
                                                  float* __restrict__ comb) {
  const int idx = blockIdx.x * 256 + threadIdx.x;  // 4*8*64*64 = 131072
  if (idx >= 4 * 8 * 64 * 64) return;
  const int j = idx & 63, i = (idx >> 6) & 63, h = (idx >> 12) & 7, ty = idx >> 15;
  float v;
  if (i < 49 && j < 49) {
    const int iy = i / 7, ix = i - iy * 7, jy = j / 7, jx = j - jy * 7;
    const int ridx = (iy - jy + 6) * 13 + (ix - jx + 6);
    v = rel_table[ridx * 8 + h];
    const int wh = (ty & 2) ? 7 : 0, ww = (ty & 1) ? 7 : 0;
    const int irg = reg3(wh * 7 + iy) * 3 + reg3(ww * 7 + ix);
    const int jrg = reg3(wh * 7 + jy) * 3 + reg3(ww * 7 + jx);
    if (irg != jrg) v -= 100.f;
  } else {
    v = -1e30f;  // padding: exp(-inf) = 0 for j>=49; rows i>=49 harmless
  }
  comb[idx] = v;
}

// ---------------------------------------------------------------------------
// LayerNorm over 256 ch, one wave per token; optional (-3,-3) cyclic shift +
// window partition on the output index. out: bf16 (token, 256) row-major.
__global__ __launch_bounds__(256) void ln_shift(const float* __restrict__ x,
                                                const float* __restrict__ g,
                                                const float* __restrict__ bta,
                                                ushort* __restrict__ out, int shifted) {
  const int wid = threadIdx.x >> 6, lane = threadIdx.x & 63;
  const int t = blockIdx.x * 4 + wid;           // output token (windowed order if shifted)
  int src;
  if (shifted) {
    int win = t / 49, n = t - win * 49;
    int bb = win >> 6, wh = (win >> 3) & 7, ww = win & 7;
    int wy = n / 7, wx = n - wy * 7;
    int r = wh * 7 + wy + 3; if (r >= 56) r -= 56;
    int c = ww * 7 + wx + 3; if (c >= 56) c -= 56;
    src = bb * 3136 + r * 56 + c;
  } else {
    src = t;
  }
  const float4 v = *(const float4*)(x + (size_t)src * 256 + lane * 4);
  float s  = v.x + v.y + v.z + v.w;
  float s2 = v.x * v.x + v.y * v.y + v.z * v.z + v.w * v.w;
#pragma unroll
  for (int m = 32; m; m >>= 1) { s += __shfl_xor(s, m); s2 += __shfl_xor(s2, m); }
  const float mean = s * (1.f / 256.f);
  const float var  = s2 * (1.f / 256.f) - mean * mean;
  const float rs   = rsqrtf(var + 1e-5f);
  const float4 gv = *(const float4*)(g + lane * 4);
  const float4 bv = *(const float4*)(bta + lane * 4);
  ushort4 o;
  o.x = f2bf((v.x - mean) * rs * gv.x + bv.x);
  o.y = f2bf((v.y - mean) * rs * gv.y + bv.y);
  o.z = f2bf((v.z - mean) * rs * gv.z + bv.z);
  o.w = f2bf((v.w - mean) * rs * gv.w + bv.w);
  *(ushort4*)(out + (size_t)t * 256 + lane * 4) = o;
}

// ---------------------------------------------------------------------------
// Generic bf16 GEMM (R7 form, 654 µs config): C[M,N] = A[M,K] @ B[N,K]^T,
// 128x128 tile, BK=32, 256 thr (2x2 waves), gload_lds staging, dbuf.
// __launch_bounds__(256,4) -> 4 blocks/CU.
template <class Epi>
__global__ __launch_bounds__(256, 4) void gemm_bt(const ushort* __restrict__ A,
                                                  const ushort* __restrict__ B,
                                                  int K, int NT, Epi epi) {
  __shared__ ushort lsA[2][128 * 32];
  __shared__ ushort lsB[2][128 * 32];
  const int tid = threadIdx.x;
  const int lane = tid & 63, wid = tid >> 6;
  const int quad = lane >> 4, l16 = lane & 15;
  const int wm = wid >> 1, wn = wid & 1;
  // XCD-chunked bijective remap (nwg = 784*NT, divisible by 8)
  const int lin = blockIdx.x;
  const int xcd = lin & 7, j = lin >> 3;
  const int mt = xcd * 98 + j / NT;            // 98 = 784/8 stripes per XCD
  const int nt_ = j % NT;
  const long rowA0 = (long)mt * 128;
  const long colB0 = (long)nt_ * 128;
  f4 acc[4][4];
#pragma unroll
  for (int i = 0; i < 4; ++i)
#pragma unroll
    for (int jj = 0; jj < 4; ++jj) { acc[i][jj][0] = 0.f; acc[i][jj][1] = 0.f; acc[i][jj][2] = 0.f; acc[i][jj][3] = 0.f; }
  const int lrow = lane >> 2;
  const int lk = ((lane & 3) ^ ((lane >> 3) & 3)) * 8;   // swizzled global k-chunk
  const int rsw = (quad ^ ((l16 >> 1) & 3)) * 8;         // swizzled read slot
  const int seg0 = wid * 2, seg1 = wid * 2 + 1;
  const ushort* pa0 = A + (rowA0 + seg0 * 16 + lrow) * (long)K + lk;
  const ushort* pa1 = A + (rowA0 + seg1 * 16 + lrow) * (long)K + lk;
  const ushort* pb0 = B + (colB0 + seg0 * 16 + lrow) * (long)K + lk;
  const ushort* pb1 = B + (colB0 + seg1 * 16 + lrow) * (long)K + lk;

  const int nsteps = K >> 5;
  load_lds16(pa0, &lsA[0][seg0 * 512]);
  load_lds16(pa1, &lsA[0][seg1 * 512]);
  load_lds16(pb0, &lsB[0][seg0 * 512]);
  load_lds16(pb1, &lsB[0][seg1 * 512]);
  __syncthreads();

  for (int t = 0; t < nsteps; ++t) {
    const int cur = t & 1;
    if (t + 1 < nsteps) {
      const int k1 = (t + 1) << 5;
      load_lds16(pa0 + k1, &lsA[cur ^ 1][seg0 * 512]);
      load_lds16(pa1 + k1, &lsA[cur ^ 1][seg1 * 512]);
      load_lds16(pb0 + k1, &lsB[cur ^ 1][seg0 * 512]);
      load_lds16(pb1 + k1, &lsB[cur ^ 1][seg1 * 512]);
    }
    b8 af[4], bfr[4];
#pragma unroll
    for (int ti = 0; ti < 4; ++ti)
      af[ti] = *(const b8*)&lsA[cur][(wm * 64 + ti * 16 + l16) * 32 + rsw];
#pragma unroll
    for (int tj = 0; tj < 4; ++tj)
      bfr[tj] = *(const b8*)&lsB[cur][(wn * 64 + tj * 16 + l16) * 32 + rsw];
#pragma unroll
    for (int ti = 0; ti < 4; ++ti)
#pragma unroll
      for (int tj = 0; tj < 4; ++tj)
        acc[ti][tj] = __builtin_amdgcn_mfma_f32_16x16x32_bf16(af[ti], bfr[tj], acc[ti][tj], 0, 0, 0);
    __syncthreads();
  }
  // C/D layout: row = quad*4+reg, col = lane&15 [m89/m91]
#pragma unroll
  for (int ti = 0; ti < 4; ++ti)
#pragma unroll
    for (int tj = 0; tj < 4; ++tj)
#pragma unroll
      for (int r = 0; r < 4; ++r)
        epi((int)(rowA0 + wm * 64 + ti * 16 + quad * 4 + r),
            (int)(colB0 + wn * 64 + tj * 16 + l16), acc[ti][tj][r]);
}

struct QkvEpi {
  ushort* out; const float* bias;
  __device__ void operator()(int r, int c, float v) const {
    v += bias[c];
    if (c < 256) v *= 0.17677669529663687f;  // HD^-0.5, pre-scale q
    out[(size_t)r * 768 + c] = f2bf(v);
  }
};

// ---------------------------------------------------------------------------
// Fused MLP v4: out += fc2(gelu(fc1(xw2)+b1))+b2 per 32-token stripe.
// 512 thr / 8 waves, 3136 blocks. LDS 64KB: A (32x256, 16KB, gemm staging
// layout) at ls[0]; H (32x1024 bf16, XOR-swizzled, 64KB) aliases it after a
// barrier. 2 blocks/CU (R13: double TLP vs 64-row stripe's 1 block/CU).
// W1/W2 FRAGMENT-MAJOR: every b8 fragment load = base + lane*16B coalesced.
// fc1: wave h owns H cols [h*128,+128), K=256 unrolled, weight loads in 2
// groups of 4 (reg budget). fc2: wave h owns out cols [h*32,+32), K=1024.
// 3 barriers per block, none inside K-loops.
__global__ __launch_bounds__(512, 4) void mlp2(const ushort* __restrict__ A,
                                               const ushort* __restrict__ w1f,
                                               const float* __restrict__ b1,
                                               const ushort* __restrict__ w2f,
                                               const float* __restrict__ b2,
                                               float* __restrict__ out) {
  extern __shared__ __align__(16) ushort ls[];   // 64KB
  ushort* lsA = ls;          // [0, 8192) ushorts = 16KB, dead after fc1
  ushort* lsH = ls;          // [0, 32768) ushorts = 64KB, written after bar
  const int tid = threadIdx.x, lane = tid & 63, h = tid >> 6;
  const int quad = lane >> 4, l16 = lane & 15;
  const long r0 = (long)blockIdx.x * 32;
  const int lrow = lane >> 2;
  const int lk = ((lane & 3) ^ ((lane >> 3) & 3)) * 8;   // swizzled global k-chunk
  const int rsw = (quad ^ ((l16 >> 1) & 3)) * 8;         // swizzled read slot
  // fragment-major weight bases: wave h's slice, per-lane 16B (coalesced)
  const ushort* w1b = w1f + ((size_t)h << 15) + lane * 8;
  const ushort* w2b = w2f + ((size_t)h << 15) + lane * 8;

  // ---- stage A (32x256, 16KB): wave h stages k-chunk h (2 segments x 1KB)
#pragma unroll
  for (int seg = 0; seg < 2; ++seg)
    load_lds16(A + (r0 + seg * 16 + lrow) * 256 + h * 32 + lk,
               &lsA[h * 1024 + seg * 512]);
  __syncthreads();   // A resident block-wide (barrier drains vmcnt)

  // ---- fc1: a1[2][8] = A @ W1^T for cols [h*128, +128), K=256 unrolled
  f4 a1[2][8];
#pragma unroll
  for (int ti = 0; ti < 2; ++ti)
#pragma unroll
    for (int tn = 0; tn < 8; ++tn) { a1[ti][tn][0] = 0.f; a1[ti][tn][1] = 0.f; a1[ti][tn][2] = 0.f; a1[ti][tn][3] = 0.f; }
#pragma unroll
  for (int kc = 0; kc < 8; ++kc) {
    b8 af[2];
#pragma unroll
    for (int ti = 0; ti < 2; ++ti)
      af[ti] = *(const b8*)&lsA[kc * 1024 + (ti * 16 + l16) * 32 + rsw];
#pragma unroll
    for (int g = 0; g < 2; ++g) {       // 2 groups of 4 weight fragments
      b8 bw[4];
#pragma unroll
      for (int tn = 0; tn < 4; ++tn)
        bw[tn] = *(const b8*)(w1b + (((g * 4 + tn) * 8 + kc) << 9));
#pragma unroll
      for (int ti = 0; ti < 2; ++ti)
#pragma unroll
        for (int tn = 0; tn < 4; ++tn)
          a1[ti][g * 4 + tn] = __builtin_amdgcn_mfma_f32_16x16x32_bf16(af[ti], bw[tn], a1[ti][g * 4 + tn], 0, 0, 0);
    }
  }
  __syncthreads();   // ALL waves done reading A before H overwrites it

  // ---- bias + exact gelu -> H (16B-chunk XOR swizzle: cc ^= row&7)
  float b1v[8];
#pragma unroll
  for (int tn = 0; tn < 8; ++tn) b1v[tn] = b1[h * 128 + tn * 16 + l16];
#pragma unroll
  for (int ti = 0; ti < 2; ++ti)
#pragma unroll
    for (int tn = 0; tn < 8; ++tn)
#pragma unroll
      for (int rr = 0; rr < 4; ++rr) {
        const int row = ti * 16 + quad * 4 + rr;
        const int cc = h * 16 + tn * 2 + (l16 >> 3);   // 16B chunk of col
        float v = a1[ti][tn][rr] + b1v[tn];
        v = 0.5f * v * (1.f + erff(v * 0.70710678118654752f));
        lsH[row * 1024 + (((cc ^ (row & 7)) << 3) | (l16 & 7))] = f2bf(v);
      }
  __syncthreads();   // H visible block-wide

  // ---- fc2: a2[2][2] = H @ W2^T for cols [h*32, +32), K=1024
  f4 a2[2][2];
#pragma unroll
  for (int ti = 0; ti < 2; ++ti)
#pragma unroll
    for (int tn = 0; tn < 2; ++tn) { a2[ti][tn][0] = 0.f; a2[ti][tn][1] = 0.f; a2[ti][tn][2] = 0.f; a2[ti][tn][3] = 0.f; }
#pragma unroll 8
  for (int kc = 0; kc < 32; ++kc) {
    b8 bw2[2];
#pragma unroll
    for (int tn = 0; tn < 2; ++tn)
      bw2[tn] = *(const b8*)(w2b + ((tn * 32 + kc) << 9));
#pragma unroll
    for (int ti = 0; ti < 2; ++ti) {
      const int row = ti * 16 + l16;
      const b8 pa = *(const b8*)&lsH[row * 1024 + ((((kc * 4 + quad)) ^ (row & 7)) << 3)];
#pragma unroll
      for (int tn = 0; tn < 2; ++tn)
        a2[ti][tn] = __builtin_amdgcn_mfma_f32_16x16x32_bf16(pa, bw2[tn], a2[ti][tn], 0, 0, 0);
    }
  }

  // ---- epilogue: out += C + b2
#pragma unroll
  for (int tn = 0; tn < 2; ++tn) {
    const float bb = b2[h * 32 + tn * 16 + l16];
#pragma unroll
    for (int ti = 0; ti < 2; ++ti)
#pragma unroll
      for (int rr = 0; rr < 4; ++rr) {
        const size_t i = (size_t)(r0 + ti * 16 + quad * 4 + rr) * 256 + h * 32 + tn * 16 + l16;
        out[i] += a2[ti][tn][rr] + bb;
      }
  }
}

// ---------------------------------------------------------------------------
// Attention + proj + residual + LN2, one block per window (512 thr), one
// wave/head. qkv rows: [q(256, pre-scaled) | k(256) | v(256)] bf16.
// Writes x_after (fp32, d_out) and LN2(x_after) (bf16, fc1's A) directly.
__global__ __launch_bounds__(512) void attn_proj(const ushort* __restrict__ qkv,
                                                 const float* __restrict__ comb,
                                                 const ushort* __restrict__ projw,
                                                 const float* __restrict__ projb,
                                                 const float* __restrict__ x_in,
                                                 const float* __restrict__ n2g,
                                                 const float* __restrict__ n2b,
                                                 float* __restrict__ x_out,
                                                 ushort* __restrict__ xw2) {
  __shared__ ushort sbuf[32768];  // 64KB: P (8 x 64x64) ; O staging ; fp32 x_after
  const int win = blockIdx.x;
  const int b = win >> 6, wh = (win >> 3) & 7, ww = win & 7;
  const int tid = threadIdx.x, lane = tid & 63, h = tid >> 6;
  const int quad = lane >> 4, l16 = lane & 15;
  const size_t wbase = (size_t)win * 49 * 768;

  // ---- Phase 1: S = (q*scale) @ k^T, padded to 64x64, K=32 (one MFMA/tile)
  b8 af[4], bfr[4];
#pragma unroll
  for (int ti = 0; ti < 4; ++ti) {
    const int tok = ti * 16 + l16;
    af[ti] = (tok < 49) ? *(const b8*)(qkv + wbase + (size_t)tok * 768 + h * 32 + quad * 8)
                        : zero_b8();
  }
#pragma unroll
  for (int tj = 0; tj < 4; ++tj) {
    const int key = tj * 16 + l16;
    bfr[tj] = (key < 49) ? *(const b8*)(qkv + wbase + (size_t)key * 768 + 256 + h * 32 + quad * 8)
                         : zero_b8();
  }
  f4 S[4][4];
#pragma unroll
  for (int ti = 0; ti < 4; ++ti)
#pragma unroll
    for (int tj = 0; tj < 4; ++tj) {
      S[ti][tj][0] = 0.f; S[ti][tj][1] = 0.f; S[ti][tj][2] = 0.f; S[ti][tj][3] = 0.f;
      S[ti][tj] = __builtin_amdgcn_mfma_f32_16x16x32_bf16(af[ti], bfr[tj], S[ti][tj], 0, 0, 0);
    }

  // ---- Phase 2: + precombined bias/mask table (coalesced L2 reads), row
  // softmax, P -> LDS bf16 with 16B-chunk XOR swizzle (chunk ^= row&7).
  ushort* P = sbuf + h * 4096;  // this head's 64x64
  const float* cmb = comb + ((((wh == 7) ? 2 : 0) + ((ww == 7) ? 1 : 0)) * 8 + h) * 4096;
#pragma unroll
  for (int ti = 0; ti < 4; ++ti) {
#pragma unroll
    for (int r = 0; r < 4; ++r) {
      const int i = ti * 16 + quad * 4 + r;
      const float* crow = cmb + i * 64 + l16;
      float sv[4];
#pragma unroll
      for (int tj = 0; tj < 4; ++tj) sv[tj] = S[ti][tj][r] + crow[tj * 16];
      float m = fmaxf(fmaxf(sv[0], sv[1]), fmaxf(sv[2], sv[3]));
#pragma unroll
      for (int d = 1; d < 16; d <<= 1) m = fmaxf(m, __shfl_xor(m, d));
      float sum = 0.f;
#pragma unroll
      for (int tj = 0; tj < 4; ++tj) { sv[tj] = __expf(sv[tj] - m); sum += sv[tj]; }
#pragma unroll
      for (int d = 1; d < 16; d <<= 1) sum += __shfl_xor(sum, d);
      const float inv = 1.f / sum;
      const int swz = i & 7, off = l16 & 7, cb = l16 >> 3;
#pragma unroll
      for (int tj = 0; tj < 4; ++tj) {
        const int cc = tj * 2 + cb;
        P[i * 64 + (((cc ^ swz) << 3) | off)] = f2bf(sv[tj] * inv);
      }
    }
  }

  // ---- Phase 3: O = P @ V (K=64 keys, 2 MFMAs per 16x16 out tile)
  f4 O[4][2];
#pragma unroll
  for (int ti = 0; ti < 4; ++ti)
#pragma unroll
    for (int tn = 0; tn < 2; ++tn) { O[ti][tn][0] = 0.f; O[ti][tn][1] = 0.f; O[ti][tn][2] = 0.f; O[ti][tn][3] = 0.f; }
#pragma unroll
  for (int kt = 0; kt < 2; ++kt) {
    b8 vb[2];
#pragma unroll
    for (int tn = 0; tn < 2; ++tn)
#pragma unroll
      for (int j = 0; j < 8; ++j) {
        const int key = kt * 32 + quad * 8 + j;  // B-frag: b[j]=V[k=quad*8+j][n=lane&15]
        vb[tn][j] = (key < 49)
            ? bfb(qkv[wbase + (size_t)key * 768 + 512 + h * 32 + tn * 16 + l16])
            : (__bf16)0.f;
      }
#pragma unroll
    for (int ti = 0; ti < 4; ++ti) {
      const int row = ti * 16 + l16;
      const b8 pa = *(const b8*)(P + row * 64 + (((kt * 4 + quad) ^ (row & 7)) << 3));
#pragma unroll
      for (int tn = 0; tn < 2; ++tn)
        O[ti][tn] = __builtin_amdgcn_mfma_f32_16x16x32_bf16(pa, vb[tn], O[ti][tn], 0, 0, 0);
    }
  }

  // ---- Phase 4: stage O (64 x 256 bf16) in LDS, XOR-swizzled (aliases P)
  __syncthreads();
  ushort* ob = sbuf;
#pragma unroll
  for (int ti = 0; ti < 4; ++ti)
#pragma unroll
    for (int tn = 0; tn < 2; ++tn)
#pragma unroll
      for (int r = 0; r < 4; ++r) {
        const int tok = ti * 16 + quad * 4 + r;
        const int cc = h * 4 + tn * 2 + (l16 >> 3);
        ob[tok * 256 + (((cc ^ (tok & 7)) << 3) | (l16 & 7))] = f2bf(O[ti][tn][r]);
      }
  __syncthreads();

  // ---- Phase 5: proj: (64x256) @ projw(256,256)^T; wave h owns 32 out cols
  f4 C[4][2];
#pragma unroll
  for (int ti = 0; ti < 4; ++ti)
#pragma unroll
    for (int tn = 0; tn < 2; ++tn) { C[ti][tn][0] = 0.f; C[ti][tn][1] = 0.f; C[ti][tn][2] = 0.f; C[ti][tn][3] = 0.f; }
  for (int k0 = 0; k0 < 256; k0 += 32) {
    b8 bw[2];
#pragma unroll
    for (int tn = 0; tn < 2; ++tn)
      bw[tn] = *(const b8*)(projw + (size_t)(h * 32 + tn * 16 + l16) * 256 + k0 + quad * 8);
#pragma unroll
    for (int ti = 0; ti < 4; ++ti) {
      const int row = ti * 16 + l16;
      const b8 pa = *(const b8*)(ob + row * 256 + ((((k0 >> 3) + quad) ^ (row & 7)) << 3));
#pragma unroll
      for (int tn = 0; tn < 2; ++tn)
        C[ti][tn] = __builtin_amdgcn_mfma_f32_16x16x32_bf16(pa, bw[tn], C[ti][tn], 0, 0, 0);
    }
  }

  // ---- Phase 6: stage proj output (64x256 fp32, 64KB) in LDS, float4-chunk
  // XOR swizzle (chunk ^= tok&7) to spread write banks.
  __syncthreads();  // all waves done reading ob
  float* fbuf = (float*)sbuf;
#pragma unroll
  for (int ti = 0; ti < 4; ++ti)
#pragma unroll
    for (int r = 0; r < 4; ++r) {
      const int tok = ti * 16 + quad * 4 + r;
      const int swz = tok & 7;
#pragma unroll
      for (int tn = 0; tn < 2; ++tn) {
        const int c4 = h * 8 + tn * 4 + (l16 >> 2);
        fbuf[tok * 256 + (((c4 ^ swz) << 2) | (l16 & 3))] = C[ti][tn][r];
      }
    }
  __syncthreads();

  // ---- Phase 7: per-token: x_after = proj + projb + shortcut (inverse
  // shift), store fp32; fused LN2 -> bf16 xw2 (raster token order).
  for (int t = h; t < 49; t += 8) {
    const int wy = t / 7, wx = t - wy * 7;
    int rr = wh * 7 + wy + 3; if (rr >= 56) rr -= 56;
    int cc = ww * 7 + wx + 3; if (cc >= 56) cc -= 56;
    const size_t base = ((size_t)b * 3136 + rr * 56 + cc) * 256;
    // swizzled read: location chunk lane^(t&7) holds column chunk `lane`
    float4 v = *(float4*)&fbuf[t * 256 + ((lane ^ (t & 7)) << 2)];
    const float4 pb = *(const float4*)(projb + lane * 4);
    const float4 xr = *(const float4*)(x_in + base + lane * 4);
    v.x += pb.x + xr.x; v.y += pb.y + xr.y; v.z += pb.z + xr.z; v.w += pb.w + xr.w;
    *(float4*)(x_out + base + lane * 4) = v;
    float s  = v.x + v.y + v.z + v.w;
    float s2 = v.x * v.x + v.y * v.y + v.z * v.z + v.w * v.w;
#pragma unroll
    for (int m = 32; m; m >>= 1) { s += __shfl_xor(s, m); s2 += __shfl_xor(s2, m); }
    const float mean = s * (1.f / 256.f);
    const float var  = s2 * (1.f / 256.f) - mean * mean;
    const float rs   = rsqrtf(var + 1e-5f);
    const float4 gv = *(const float4*)(n2g + lane * 4);
    const float4 bv = *(const float4*)(n2b + lane * 4);
    ushort4 o;
    o.x = f2bf((v.x - mean) * rs * gv.x + bv.x);
    o.y = f2bf((v.y - mean) * rs * gv.y + bv.y);
    o.z = f2bf((v.z - mean) * rs * gv.z + bv.z);
    o.w = f2bf((v.w - mean) * rs * gv.w + bv.w);
    *(ushort4*)(xw2 + base + lane * 4) = o;
  }
}

// ---------------------------------------------------------------------------
extern "C" void kernel_launch(void* const* d_in, const int* in_sizes, int n_in,
                              void* d_out, int out_size, void* d_ws, size_t ws_size,
                              hipStream_t stream) {
  const float* x     = (const float*)d_in[0];
  const float* n1g   = (const float*)d_in[1];
  const float* n1b   = (const float*)d_in[2];
  const float* qkvw  = (const float*)d_in[3];
  const float* qkvb  = (const float*)d_in[4];
  const float* relt  = (const float*)d_in[5];
  const float* projw = (const float*)d_in[6];
  const float* projb = (const float*)d_in[7];
  const float* n2g   = (const float*)d_in[8];
  const float* n2b   = (const float*)d_in[9];
  const float* fc1w  = (const float*)d_in[10];
  const float* fc1b  = (const float*)d_in[11];
  const float* fc2w  = (const float*)d_in[12];
  const float* fc2b  = (const float*)d_in[13];
  float* out = (float*)d_out;
  char* ws = (char*)d_ws;

  // ws layout:
  //   [0, 51.4MB)        xw: LN1 windowed bf16 A; reused as LN2 output (xw2)
  //   [51.4, 205.5MB)    qkv bf16 (154.1MB)
  //   [205.5, 206.0MB)   comb bias/mask table (512KB)
  //   [256.9, 258.5MB)   bf16 weights (wqkv, wproj row-major; wfc1/wfc2
  //                      fragment-major for mlp2)
  ushort* xw     = (ushort*)ws;
  ushort* qkv    = (ushort*)(ws + 51380224);
  float*  comb   = (float*)(ws + 205520896);   // after qkv's 154,140,672 bytes
  ushort* wqkv   = (ushort*)(ws + 51380224 + 205520896);
  ushort* wproj  = wqkv + 196608;
  ushort* wfc1   = wproj + 65536;    // fragment-major (1024x256, K32=8)
  ushort* wfc2   = wfc1 + 262144;    // fragment-major (256x1024, K32=32)

  static bool attr_done = false;
  if (!attr_done) {
    attr_done = true;
    hipFuncSetAttribute(reinterpret_cast<const void*>(&mlp2),
                        hipFuncAttributeMaxDynamicSharedMemorySize, 65536);
  }

  cast_w<<<512, 256, 0, stream>>>(qkvw, wqkv, 196608, projw, wproj, 65536);
  cast_frag<<<1024, 256, 0, stream>>>(fc1w, wfc1, 8);    // 1024x256
  cast_frag<<<1024, 256, 0, stream>>>(fc2w, wfc2, 32);   // 256x1024
  build_bias<<<512, 256, 0, stream>>>(relt, comb);
  // LN1 + shift + window partition -> bf16
  ln_shift<<<25088, 256, 0, stream>>>(x, n1g, n1b, xw, 1);
  // qkv: (100352,256) @ (768,256)^T — 1D grid, XCD-chunked, NT=6
  gemm_bt<<<4704, 256, 0, stream>>>(xw, wqkv, 256, 6, QkvEpi{qkv, qkvb});
  // attention + proj + residual + inverse shift + LN2 -> d_out, xw (bf16)
  attn_proj<<<2048, 512, 0, stream>>>(qkv, comb, wproj, projb, x, n2g, n2b, out, xw);
  // fused MLP v4 (32-token stripes, 2 blocks/CU): out += fc2(gelu(fc1(xw2)))
  mlp2<<<3136, 512, 65536, stream>>>(xw, wfc1, fc1b, wfc2, fc2b, out);
}

// Round 14
// 564.607 us; speedup vs baseline: 1.3470x; 1.0346x over previous
//
#include <hip/hip_runtime.h>

// ---------------------------------------------------------------------------
// Swin block, MI355X bf16-MFMA implementation.
// Shapes: B=32, H=W=56, DIM=256, WS=7, SHIFT=3, NH=8, HD=32, N=49, nW=64,
// Bw=2048, tokens T=100352.
// R1: attn_proj comb table + swizzles / R2: gemm dbuf + XCD grid (678)
// R7: launch_bounds(256,4): 654 / R12: fragment-major MLP weights: 617.8
// R13: 32-token mlp2 stripes -> 2 blocks/CU: 584.1 (best)
// R14: (a) gelu via tanh-form (__expf + v_rcp, ~9 ops vs erff's ~30) —
//      gelu was the dominant per-wave term (≈2500 cyc vs 1230 MFMA);
//      (b) fragment-major wproj for attn phase 5 (last R8-style gather).
// ---------------------------------------------------------------------------

typedef float f4 __attribute__((ext_vector_type(4)));
typedef __bf16 b8 __attribute__((ext_vector_type(8)));

#define DEV static __device__ __forceinline__

DEV ushort f2bf(float f) {
  union { __bf16 b; ushort u; } c; c.b = (__bf16)f;   // HW v_cvt, RNE
  return c.u;
}
DEV __bf16 bfb(ushort u) { union { ushort u; __bf16 b; } c; c.u = u; return c.b; }
DEV b8 zero_b8() {
  b8 z;
#pragma unroll
  for (int i = 0; i < 8; ++i) z[i] = (__bf16)0.f;
  return z;
}
DEV void load_lds16(const void* g, void* l) {
  // lane i's 16B land at ldsbase + i*16 (wave-uniform base) [m97/m104]
  __builtin_amdgcn_global_load_lds(
      (const __attribute__((address_space(1))) unsigned int*)g,
      (__attribute__((address_space(3))) unsigned int*)l, 16, 0, 0);
}
DEV int reg3(int t) { return t < 49 ? 0 : (t < 53 ? 1 : 2); }  // shift-mask region row/col id
// tanh-form gelu: v * e/(e+1), e = exp(2*0.79788456*(v + 0.044715 v^3)).
// ~9 VALU ops using HW v_exp + v_rcp. |err vs exact| <= ~1e-3, below the
// bf16 rounding already applied to H.
DEV float gelu_f(float v) {
  const float u2 = v * fmaf(v * v, 0.0713548163f, 1.5957691216f);
  const float e = __expf(u2);
  return v * (1.f - __builtin_amdgcn_rcpf(e + 1.f));
}

// ---------------------------------------------------------------------------
// weights fp32 -> bf16 (row-major: qkv, consumed via gload_lds)
__global__ __launch_bounds__(256) void cast_w(const float* a, ushort* oa, int na) {
  for (int i = blockIdx.x * 256 + threadIdx.x; i < na; i += gridDim.x * 256)
    oa[i] = f2bf(a[i]);
}

// ---------------------------------------------------------------------------
// weights fp32 -> bf16 FRAGMENT-MAJOR: element (col=ct*16+l16,
// k=kc*32+quad*8+j) of W[N][K] stored at ((ct*K32+kc)*64 + lane)*8 + j,
// lane = quad*16+l16. A wave's b8 fragment read becomes base + lane*16B
// (coalesced 1KB), replacing a 16-line row-stride gather.
__global__ __launch_bounds__(256) void cast_frag(const float* __restrict__ w,
                                                 ushort* __restrict__ wf, int K32) {
  const int o = blockIdx.x * 256 + threadIdx.x;   // grid sized exactly N*K
  const int q = o & 511;
  const int j = q & 7, l16 = (q >> 3) & 15, quad = q >> 7;
  const int t = o >> 9;
  const int kc = t % K32, ct = t / K32;
  const int K = K32 << 5;
  wf[o] = f2bf(w[(size_t)(ct * 16 + l16) * K + kc * 32 + quad * 8 + j]);
}

// ---------------------------------------------------------------------------
// comb[type][h][i][j]: rel-pos bias + shift mask + pad (-1e30), fp32.
// type = (wh==7)*2 + (ww==7) — only 4 distinct window mask patterns exist.
__global__ __launch_bounds__(256) void build_bias(const float* __restrict__ rel_table,
                                                  float* __restrict__ comb) {
  const int idx = blockIdx.x * 256 + threadIdx.x;  // 4*8*64*64 = 131072
  if (idx >= 4 * 8 * 64 * 64) return;
  const int j = idx & 63, i = (idx >> 6) & 63, h = (idx >> 12) & 7, ty = idx >> 15;
  float v;
  if (i < 49 && j < 49) {
    const int iy = i / 7, ix = i - iy * 7, jy = j / 7, jx = j - jy * 7;
    const int ridx = (iy - jy + 6) * 13 + (ix - jx + 6);
    v = rel_table[ridx * 8 + h];
    const int wh = (ty & 2) ? 7 : 0, ww = (ty & 1) ? 7 : 0;
    const int irg = reg3(wh * 7 + iy) * 3 + reg3(ww * 7 + ix);
    const int jrg = reg3(wh * 7 + jy) * 3 + reg3(ww * 7 + jx);
    if (irg != jrg) v -= 100.f;
  } else {
    v = -1e30f;  // padding: exp(-inf) = 0 for j>=49; rows i>=49 harmless
  }
  comb[idx] = v;
}

// ---------------------------------------------------------------------------
// LayerNorm over 256 ch, one wave per token; optional (-3,-3) cyclic shift +
// window partition on the output index. out: bf16 (token, 256) row-major.
__global__ __launch_bounds__(256) void ln_shift(const float* __restrict__ x,
                                                const float* __restrict__ g,
                                                const float* __restrict__ bta,
                                                ushort* __restrict__ out, int shifted) {
  const int wid = threadIdx.x >> 6, lane = threadIdx.x & 63;
  const int t = blockIdx.x * 4 + wid;           // output token (windowed order if shifted)
  int src;
  if (shifted) {
    int win = t / 49, n = t - win * 49;
    int bb = win >> 6, wh = (win >> 3) & 7, ww = win & 7;
    int wy = n / 7, wx = n - wy * 7;
    int r = wh * 7 + wy + 3; if (r >= 56) r -= 56;
    int c = ww * 7 + wx + 3; if (c >= 56) c -= 56;
    src = bb * 3136 + r * 56 + c;
  } else {
    src = t;
  }
  const float4 v = *(const float4*)(x + (size_t)src * 256 + lane * 4);
  float s  = v.x + v.y + v.z + v.w;
  float s2 = v.x * v.x + v.y * v.y + v.z * v.z + v.w * v.w;
#pragma unroll
  for (int m = 32; m; m >>= 1) { s += __shfl_xor(s, m); s2 += __shfl_xor(s2, m); }
  const float mean = s * (1.f / 256.f);
  const float var  = s2 * (1.f / 256.f) - mean * mean;
  const float rs   = rsqrtf(var + 1e-5f);
  const float4 gv = *(const float4*)(g + lane * 4);
  const float4 bv = *(const float4*)(bta + lane * 4);
  ushort4 o;
  o.x = f2bf((v.x - mean) * rs * gv.x + bv.x);
  o.y = f2bf((v.y - mean) * rs * gv.y + bv.y);
  o.z = f2bf((v.z - mean) * rs * gv.z + bv.z);
  o.w = f2bf((v.w - mean) * rs * gv.w + bv.w);
  *(ushort4*)(out + (size_t)t * 256 + lane * 4) = o;
}

// ---------------------------------------------------------------------------
// Generic bf16 GEMM (R7 form, 654 µs config): C[M,N] = A[M,K] @ B[N,K]^T,
// 128x128 tile, BK=32, 256 thr (2x2 waves), gload_lds staging, dbuf.
// __launch_bounds__(256,4) -> 4 blocks/CU.
template <class Epi>
__global__ __launch_bounds__(256, 4) void gemm_bt(const ushort* __restrict__ A,
                                                  const ushort* __restrict__ B,
                                                  int K, int NT, Epi epi) {
  __shared__ ushort lsA[2][128 * 32];
  __shared__ ushort lsB[2][128 * 32];
  const int tid = threadIdx.x;
  const int lane = tid & 63, wid = tid >> 6;
  const int quad = lane >> 4, l16 = lane & 15;
  const int wm = wid >> 1, wn = wid & 1;
  // XCD-chunked bijective remap (nwg = 784*NT, divisible by 8)
  const int lin = blockIdx.x;
  const int xcd = lin & 7, j = lin >> 3;
  const int mt = xcd * 98 + j / NT;            // 98 = 784/8 stripes per XCD
  const int nt_ = j % NT;
  const long rowA0 = (long)mt * 128;
  const long colB0 = (long)nt_ * 128;
  f4 acc[4][4];
#pragma unroll
  for (int i = 0; i < 4; ++i)
#pragma unroll
    for (int jj = 0; jj < 4; ++jj) { acc[i][jj][0] = 0.f; acc[i][jj][1] = 0.f; acc[i][jj][2] = 0.f; acc[i][jj][3] = 0.f; }
  const int lrow = lane >> 2;
  const int lk = ((lane & 3) ^ ((lane >> 3) & 3)) * 8;   // swizzled global k-chunk
  const int rsw = (quad ^ ((l16 >> 1) & 3)) * 8;         // swizzled read slot
  const int seg0 = wid * 2, seg1 = wid * 2 + 1;
  const ushort* pa0 = A + (rowA0 + seg0 * 16 + lrow) * (long)K + lk;
  const ushort* pa1 = A + (rowA0 + seg1 * 16 + lrow) * (long)K + lk;
  const ushort* pb0 = B + (colB0 + seg0 * 16 + lrow) * (long)K + lk;
  const ushort* pb1 = B + (colB0 + seg1 * 16 + lrow) * (long)K + lk;

  const int nsteps = K >> 5;
  load_lds16(pa0, &lsA[0][seg0 * 512]);
  load_lds16(pa1, &lsA[0][seg1 * 512]);
  load_lds16(pb0, &lsB[0][seg0 * 512]);
  load_lds16(pb1, &lsB[0][seg1 * 512]);
  __syncthreads();

  for (int t = 0; t < nsteps; ++t) {
    const int cur = t & 1;
    if (t + 1 < nsteps) {
      const int k1 = (t + 1) << 5;
      load_lds16(pa0 + k1, &lsA[cur ^ 1][seg0 * 512]);
      load_lds16(pa1 + k1, &lsA[cur ^ 1][seg1 * 512]);
      load_lds16(pb0 + k1, &lsB[cur ^ 1][seg0 * 512]);
      load_lds16(pb1 + k1, &lsB[cur ^ 1][seg1 * 512]);
    }
    b8 af[4], bfr[4];
#pragma unroll
    for (int ti = 0; ti < 4; ++ti)
      af[ti] = *(const b8*)&lsA[cur][(wm * 64 + ti * 16 + l16) * 32 + rsw];
#pragma unroll
    for (int tj = 0; tj < 4; ++tj)
      bfr[tj] = *(const b8*)&lsB[cur][(wn * 64 + tj * 16 + l16) * 32 + rsw];
#pragma unroll
    for (int ti = 0; ti < 4; ++ti)
#pragma unroll
      for (int tj = 0; tj < 4; ++tj)
        acc[ti][tj] = __builtin_amdgcn_mfma_f32_16x16x32_bf16(af[ti], bfr[tj], acc[ti][tj], 0, 0, 0);
    __syncthreads();
  }
  // C/D layout: row = quad*4+reg, col = lane&15 [m89/m91]
#pragma unroll
  for (int ti = 0; ti < 4; ++ti)
#pragma unroll
    for (int tj = 0; tj < 4; ++tj)
#pragma unroll
      for (int r = 0; r < 4; ++r)
        epi((int)(rowA0 + wm * 64 + ti * 16 + quad * 4 + r),
            (int)(colB0 + wn * 64 + tj * 16 + l16), acc[ti][tj][r]);
}

struct QkvEpi {
  ushort* out; const float* bias;
  __device__ void operator()(int r, int c, float v) const {
    v += bias[c];
    if (c < 256) v *= 0.17677669529663687f;  // HD^-0.5, pre-scale q
    out[(size_t)r * 768 + c] = f2bf(v);
  }
};

// ---------------------------------------------------------------------------
// Fused MLP v4: out += fc2(gelu(fc1(xw2)+b1))+b2 per 32-token stripe.
// 512 thr / 8 waves, 3136 blocks, LDS 64KB (A 16KB aliased under H 64KB),
// 2 blocks/CU. W1/W2 FRAGMENT-MAJOR (coalesced base+lane*16B fragments).
// R14: gelu via tanh-form (gelu_f) — cuts the dominant VALU chain ~3x.
__global__ __launch_bounds__(512, 4) void mlp2(const ushort* __restrict__ A,
                                               const ushort* __restrict__ w1f,
                                               const float* __restrict__ b1,
                                               const ushort* __restrict__ w2f,
                                               const float* __restrict__ b2,
                                               float* __restrict__ out) {
  extern __shared__ __align__(16) ushort ls[];   // 64KB
  ushort* lsA = ls;          // [0, 8192) ushorts = 16KB, dead after fc1
  ushort* lsH = ls;          // [0, 32768) ushorts = 64KB, written after bar
  const int tid = threadIdx.x, lane = tid & 63, h = tid >> 6;
  const int quad = lane >> 4, l16 = lane & 15;
  const long r0 = (long)blockIdx.x * 32;
  const int lrow = lane >> 2;
  const int lk = ((lane & 3) ^ ((lane >> 3) & 3)) * 8;   // swizzled global k-chunk
  const int rsw = (quad ^ ((l16 >> 1) & 3)) * 8;         // swizzled read slot
  // fragment-major weight bases: wave h's slice, per-lane 16B (coalesced)
  const ushort* w1b = w1f + ((size_t)h << 15) + lane * 8;
  const ushort* w2b = w2f + ((size_t)h << 15) + lane * 8;

  // ---- stage A (32x256, 16KB): wave h stages k-chunk h (2 segments x 1KB)
#pragma unroll
  for (int seg = 0; seg < 2; ++seg)
    load_lds16(A + (r0 + seg * 16 + lrow) * 256 + h * 32 + lk,
               &lsA[h * 1024 + seg * 512]);
  __syncthreads();   // A resident block-wide (barrier drains vmcnt)

  // ---- fc1: a1[2][8] = A @ W1^T for cols [h*128, +128), K=256 unrolled
  f4 a1[2][8];
#pragma unroll
  for (int ti = 0; ti < 2; ++ti)
#pragma unroll
    for (int tn = 0; tn < 8; ++tn) { a1[ti][tn][0] = 0.f; a1[ti][tn][1] = 0.f; a1[ti][tn][2] = 0.f; a1[ti][tn][3] = 0.f; }
#pragma unroll
  for (int kc = 0; kc < 8; ++kc) {
    b8 af[2];
#pragma unroll
    for (int ti = 0; ti < 2; ++ti)
      af[ti] = *(const b8*)&lsA[kc * 1024 + (ti * 16 + l16) * 32 + rsw];
#pragma unroll
    for (int g = 0; g < 2; ++g) {       // 2 groups of 4 weight fragments
      b8 bw[4];
#pragma unroll
      for (int tn = 0; tn < 4; ++tn)
        bw[tn] = *(const b8*)(w1b + (((g * 4 + tn) * 8 + kc) << 9));
#pragma unroll
      for (int ti = 0; ti < 2; ++ti)
#pragma unroll
        for (int tn = 0; tn < 4; ++tn)
          a1[ti][g * 4 + tn] = __builtin_amdgcn_mfma_f32_16x16x32_bf16(af[ti], bw[tn], a1[ti][g * 4 + tn], 0, 0, 0);
    }
  }
  __syncthreads();   // ALL waves done reading A before H overwrites it

  // ---- bias + gelu (tanh-form) -> H (16B-chunk XOR swizzle: cc ^= row&7)
  float b1v[8];
#pragma unroll
  for (int tn = 0; tn < 8; ++tn) b1v[tn] = b1[h * 128 + tn * 16 + l16];
#pragma unroll
  for (int ti = 0; ti < 2; ++ti)
#pragma unroll
    for (int tn = 0; tn < 8; ++tn)
#pragma unroll
      for (int rr = 0; rr < 4; ++rr) {
        const int row = ti * 16 + quad * 4 + rr;
        const int cc = h * 16 + tn * 2 + (l16 >> 3);   // 16B chunk of col
        lsH[row * 1024 + (((cc ^ (row & 7)) << 3) | (l16 & 7))] =
            f2bf(gelu_f(a1[ti][tn][rr] + b1v[tn]));
      }
  __syncthreads();   // H visible block-wide

  // ---- fc2: a2[2][2] = H @ W2^T for cols [h*32, +32), K=1024
  f4 a2[2][2];
#pragma unroll
  for (int ti = 0; ti < 2; ++ti)
#pragma unroll
    for (int tn = 0; tn < 2; ++tn) { a2[ti][tn][0] = 0.f; a2[ti][tn][1] = 0.f; a2[ti][tn][2] = 0.f; a2[ti][tn][3] = 0.f; }
#pragma unroll 8
  for (int kc = 0; kc < 32; ++kc) {
    b8 bw2[2];
#pragma unroll
    for (int tn = 0; tn < 2; ++tn)
      bw2[tn] = *(const b8*)(w2b + ((tn * 32 + kc) << 9));
#pragma unroll
    for (int ti = 0; ti < 2; ++ti) {
      const int row = ti * 16 + l16;
      const b8 pa = *(const b8*)&lsH[row * 1024 + ((((kc * 4 + quad)) ^ (row & 7)) << 3)];
#pragma unroll
      for (int tn = 0; tn < 2; ++tn)
        a2[ti][tn] = __builtin_amdgcn_mfma_f32_16x16x32_bf16(pa, bw2[tn], a2[ti][tn], 0, 0, 0);
    }
  }

  // ---- epilogue: out += C + b2
#pragma unroll
  for (int tn = 0; tn < 2; ++tn) {
    const float bb = b2[h * 32 + tn * 16 + l16];
#pragma unroll
    for (int ti = 0; ti < 2; ++ti)
#pragma unroll
      for (int rr = 0; rr < 4; ++rr) {
        const size_t i = (size_t)(r0 + ti * 16 + quad * 4 + rr) * 256 + h * 32 + tn * 16 + l16;
        out[i] += a2[ti][tn][rr] + bb;
      }
  }
}

// ---------------------------------------------------------------------------
// Attention + proj + residual + LN2, one block per window (512 thr), one
// wave/head. qkv rows: [q(256, pre-scaled) | k(256) | v(256)] bf16.
// projw is FRAGMENT-MAJOR (R14). Writes x_after (fp32, d_out) and
// LN2(x_after) (bf16, xw2) directly.
__global__ __launch_bounds__(512) void attn_proj(const ushort* __restrict__ qkv,
                                                 const float* __restrict__ comb,
                                                 const ushort* __restrict__ projwf,
                                                 const float* __restrict__ projb,
                                                 const float* __restrict__ x_in,
                                                 const float* __restrict__ n2g,
                                                 const float* __restrict__ n2b,
                                                 float* __restrict__ x_out,
                                                 ushort* __restrict__ xw2) {
  __shared__ ushort sbuf[32768];  // 64KB: P (8 x 64x64) ; O staging ; fp32 x_after
  const int win = blockIdx.x;
  const int b = win >> 6, wh = (win >> 3) & 7, ww = win & 7;
  const int tid = threadIdx.x, lane = tid & 63, h = tid >> 6;
  const int quad = lane >> 4, l16 = lane & 15;
  const size_t wbase = (size_t)win * 49 * 768;

  // ---- Phase 1: S = (q*scale) @ k^T, padded to 64x64, K=32 (one MFMA/tile)
  b8 af[4], bfr[4];
#pragma unroll
  for (int ti = 0; ti < 4; ++ti) {
    const int tok = ti * 16 + l16;
    af[ti] = (tok < 49) ? *(const b8*)(qkv + wbase + (size_t)tok * 768 + h * 32 + quad * 8)
                        : zero_b8();
  }
#pragma unroll
  for (int tj = 0; tj < 4; ++tj) {
    const int key = tj * 16 + l16;
    bfr[tj] = (key < 49) ? *(const b8*)(qkv + wbase + (size_t)key * 768 + 256 + h * 32 + quad * 8)
                         : zero_b8();
  }
  f4 S[4][4];
#pragma unroll
  for (int ti = 0; ti < 4; ++ti)
#pragma unroll
    for (int tj = 0; tj < 4; ++tj) {
      S[ti][tj][0] = 0.f; S[ti][tj][1] = 0.f; S[ti][tj][2] = 0.f; S[ti][tj][3] = 0.f;
      S[ti][tj] = __builtin_amdgcn_mfma_f32_16x16x32_bf16(af[ti], bfr[tj], S[ti][tj], 0, 0, 0);
    }

  // ---- Phase 2: + precombined bias/mask table (coalesced L2 reads), row
  // softmax, P -> LDS bf16 with 16B-chunk XOR swizzle (chunk ^= row&7).
  ushort* P = sbuf + h * 4096;  // this head's 64x64
  const float* cmb = comb + ((((wh == 7) ? 2 : 0) + ((ww == 7) ? 1 : 0)) * 8 + h) * 4096;
#pragma unroll
  for (int ti = 0; ti < 4; ++ti) {
#pragma unroll
    for (int r = 0; r < 4; ++r) {
      const int i = ti * 16 + quad * 4 + r;
      const float* crow = cmb + i * 64 + l16;
      float sv[4];
#pragma unroll
      for (int tj = 0; tj < 4; ++tj) sv[tj] = S[ti][tj][r] + crow[tj * 16];
      float m = fmaxf(fmaxf(sv[0], sv[1]), fmaxf(sv[2], sv[3]));
#pragma unroll
      for (int d = 1; d < 16; d <<= 1) m = fmaxf(m, __shfl_xor(m, d));
      float sum = 0.f;
#pragma unroll
      for (int tj = 0; tj < 4; ++tj) { sv[tj] = __expf(sv[tj] - m); sum += sv[tj]; }
#pragma unroll
      for (int d = 1; d < 16; d <<= 1) sum += __shfl_xor(sum, d);
      const float inv = 1.f / sum;
      const int swz = i & 7, off = l16 & 7, cb = l16 >> 3;
#pragma unroll
      for (int tj = 0; tj < 4; ++tj) {
        const int cc = tj * 2 + cb;
        P[i * 64 + (((cc ^ swz) << 3) | off)] = f2bf(sv[tj] * inv);
      }
    }
  }

  // ---- Phase 3: O = P @ V (K=64 keys, 2 MFMAs per 16x16 out tile)
  f4 O[4][2];
#pragma unroll
  for (int ti = 0; ti < 4; ++ti)
#pragma unroll
    for (int tn = 0; tn < 2; ++tn) { O[ti][tn][0] = 0.f; O[ti][tn][1] = 0.f; O[ti][tn][2] = 0.f; O[ti][tn][3] = 0.f; }
#pragma unroll
  for (int kt = 0; kt < 2; ++kt) {
    b8 vb[2];
#pragma unroll
    for (int tn = 0; tn < 2; ++tn)
#pragma unroll
      for (int j = 0; j < 8; ++j) {
        const int key = kt * 32 + quad * 8 + j;  // B-frag: b[j]=V[k=quad*8+j][n=lane&15]
        vb[tn][j] = (key < 49)
            ? bfb(qkv[wbase + (size_t)key * 768 + 512 + h * 32 + tn * 16 + l16])
            : (__bf16)0.f;
      }
#pragma unroll
    for (int ti = 0; ti < 4; ++ti) {
      const int row = ti * 16 + l16;
      const b8 pa = *(const b8*)(P + row * 64 + (((kt * 4 + quad) ^ (row & 7)) << 3));
#pragma unroll
      for (int tn = 0; tn < 2; ++tn)
        O[ti][tn] = __builtin_amdgcn_mfma_f32_16x16x32_bf16(pa, vb[tn], O[ti][tn], 0, 0, 0);
    }
  }

  // ---- Phase 4: stage O (64 x 256 bf16) in LDS, XOR-swizzled (aliases P)
  __syncthreads();
  ushort* ob = sbuf;
#pragma unroll
  for (int ti = 0; ti < 4; ++ti)
#pragma unroll
    for (int tn = 0; tn < 2; ++tn)
#pragma unroll
      for (int r = 0; r < 4; ++r) {
        const int tok = ti * 16 + quad * 4 + r;
        const int cc = h * 4 + tn * 2 + (l16 >> 3);
        ob[tok * 256 + (((cc ^ (tok & 7)) << 3) | (l16 & 7))] = f2bf(O[ti][tn][r]);
      }
  __syncthreads();

  // ---- Phase 5: proj (fragment-major projwf): wave h owns 32 out cols
  f4 C[4][2];
#pragma unroll
  for (int ti = 0; ti < 4; ++ti)
#pragma unroll
    for (int tn = 0; tn < 2; ++tn) { C[ti][tn][0] = 0.f; C[ti][tn][1] = 0.f; C[ti][tn][2] = 0.f; C[ti][tn][3] = 0.f; }
  const ushort* wpb = projwf + h * 8192 + lane * 8;  // ct base = h*2, K32=8
#pragma unroll
  for (int kc = 0; kc < 8; ++kc) {
    b8 bw[2];
#pragma unroll
    for (int tn = 0; tn < 2; ++tn)
      bw[tn] = *(const b8*)(wpb + ((tn * 8 + kc) << 9));
#pragma unroll
    for (int ti = 0; ti < 4; ++ti) {
      const int row = ti * 16 + l16;
      const b8 pa = *(const b8*)(ob + row * 256 + (((kc + quad * 0 + kc * 3 + quad) ^ (row & 7)) << 3));
      // NOTE: read slot = (kc*4+quad) ^ (row&7); expression kept explicit below
      (void)pa;
      const b8 pa2 = *(const b8*)(ob + row * 256 + ((((kc * 4 + quad)) ^ (row & 7)) << 3));
#pragma unroll
      for (int tn = 0; tn < 2; ++tn)
        C[ti][tn] = __builtin_amdgcn_mfma_f32_16x16x32_bf16(pa2, bw[tn], C[ti][tn], 0, 0, 0);
    }
  }

  // ---- Phase 6: stage proj output (64x256 fp32, 64KB) in LDS, float4-chunk
  // XOR swizzle (chunk ^= tok&7) to spread write banks.
  __syncthreads();  // all waves done reading ob
  float* fbuf = (float*)sbuf;
#pragma unroll
  for (int ti = 0; ti < 4; ++ti)
#pragma unroll
    for (int r = 0; r < 4; ++r) {
      const int tok = ti * 16 + quad * 4 + r;
      const int swz = tok & 7;
#pragma unroll
      for (int tn = 0; tn < 2; ++tn) {
        const int c4 = h * 8 + tn * 4 + (l16 >> 2);
        fbuf[tok * 256 + (((c4 ^ swz) << 2) | (l16 & 3))] = C[ti][tn][r];
      }
    }
  __syncthreads();

  // ---- Phase 7: per-token: x_after = proj + projb + shortcut (inverse
  // shift), store fp32; fused LN2 -> bf16 xw2 (raster token order).
  for (int t = h; t < 49; t += 8) {
    const int wy = t / 7, wx = t - wy * 7;
    int rr = wh * 7 + wy + 3; if (rr >= 56) rr -= 56;
    int cc = ww * 7 + wx + 3; if (cc >= 56) cc -= 56;
    const size_t base = ((size_t)b * 3136 + rr * 56 + cc) * 256;
    // swizzled read: location chunk lane^(t&7) holds column chunk `lane`
    float4 v = *(float4*)&fbuf[t * 256 + ((lane ^ (t & 7)) << 2)];
    const float4 pb = *(const float4*)(projb + lane * 4);
    const float4 xr = *(const float4*)(x_in + base + lane * 4);
    v.x += pb.x + xr.x; v.y += pb.y + xr.y; v.z += pb.z + xr.z; v.w += pb.w + xr.w;
    *(float4*)(x_out + base + lane * 4) = v;
    float s  = v.x + v.y + v.z + v.w;
    float s2 = v.x * v.x + v.y * v.y + v.z * v.z + v.w * v.w;
#pragma unroll
    for (int m = 32; m; m >>= 1) { s += __shfl_xor(s, m); s2 += __shfl_xor(s2, m); }
    const float mean = s * (1.f / 256.f);
    const float var  = s2 * (1.f / 256.f) - mean * mean;
    const float rs   = rsqrtf(var + 1e-5f);
    const float4 gv = *(const float4*)(n2g + lane * 4);
    const float4 bv = *(const float4*)(n2b + lane * 4);
    ushort4 o;
    o.x = f2bf((v.x - mean) * rs * gv.x + bv.x);
    o.y = f2bf((v.y - mean) * rs * gv.y + bv.y);
    o.z = f2bf((v.z - mean) * rs * gv.z + bv.z);
    o.w = f2bf((v.w - mean) * rs * gv.w + bv.w);
    *(ushort4*)(xw2 + base + lane * 4) = o;
  }
}

// ---------------------------------------------------------------------------
extern "C" void kernel_launch(void* const* d_in, const int* in_sizes, int n_in,
                              void* d_out, int out_size, void* d_ws, size_t ws_size,
                              hipStream_t stream) {
  const float* x     = (const float*)d_in[0];
  const float* n1g   = (const float*)d_in[1];
  const float* n1b   = (const float*)d_in[2];
  const float* qkvw  = (const float*)d_in[3];
  const float* qkvb  = (const float*)d_in[4];
  const float* relt  = (const float*)d_in[5];
  const float* projw = (const float*)d_in[6];
  const float* projb = (const float*)d_in[7];
  const float* n2g   = (const float*)d_in[8];
  const float* n2b   = (const float*)d_in[9];
  const float* fc1w  = (const float*)d_in[10];
  const float* fc1b  = (const float*)d_in[11];
  const float* fc2w  = (const float*)d_in[12];
  const float* fc2b  = (const float*)d_in[13];
  float* out = (float*)d_out;
  char* ws = (char*)d_ws;

  // ws layout:
  //   [0, 51.4MB)        xw: LN1 windowed bf16 A; reused as LN2 output (xw2)
  //   [51.4, 205.5MB)    qkv bf16 (154.1MB)
  //   [205.5, 206.0MB)   comb bias/mask table (512KB)
  //   [256.9, 258.5MB)   bf16 weights (wqkv row-major; wproj/wfc1/wfc2
  //                      fragment-major)
  ushort* xw     = (ushort*)ws;
  ushort* qkv    = (ushort*)(ws + 51380224);
  float*  comb   = (float*)(ws + 205520896);   // after qkv's 154,140,672 bytes
  ushort* wqkv   = (ushort*)(ws + 51380224 + 205520896);
  ushort* wproj  = wqkv + 196608;    // fragment-major (256x256, K32=8)
  ushort* wfc1   = wproj + 65536;    // fragment-major (1024x256, K32=8)
  ushort* wfc2   = wfc1 + 262144;    // fragment-major (256x1024, K32=32)

  static bool attr_done = false;
  if (!attr_done) {
    attr_done = true;
    hipFuncSetAttribute(reinterpret_cast<const void*>(&mlp2),
                        hipFuncAttributeMaxDynamicSharedMemorySize, 65536);
  }

  cast_w<<<512, 256, 0, stream>>>(qkvw, wqkv, 196608);
  cast_frag<<<256, 256, 0, stream>>>(projw, wproj, 8);   // 256x256
  cast_frag<<<1024, 256, 0, stream>>>(fc1w, wfc1, 8);    // 1024x256
  cast_frag<<<1024, 256, 0, stream>>>(fc2w, wfc2, 32);   // 256x1024
  build_bias<<<512, 256, 0, stream>>>(relt, comb);
  // LN1 + shift + window partition -> bf16
  ln_shift<<<25088, 256, 0, stream>>>(x, n1g, n1b, xw, 1);
  // qkv: (100352,256) @ (768,256)^T — 1D grid, XCD-chunked, NT=6
  gemm_bt<<<4704, 256, 0, stream>>>(xw, wqkv, 256, 6, QkvEpi{qkv, qkvb});
  // attention + proj + residual + inverse shift + LN2 -> d_out, xw (bf16)
  attn_proj<<<2048, 512, 0, stream>>>(qkv, comb, wproj, projb, x, n2g, n2b, out, xw);
  // fused MLP v4 (32-token stripes, 2 blocks/CU): out += fc2(gelu(fc1(xw2)))
  mlp2<<<3136, 512, 65536, stream>>>(xw, wfc1, fc1b, wfc2, fc2b, out);
}